// Round 8
// baseline (710.051 us; speedup 1.0000x reference)
//
#include <hip/hip_runtime.h>

#define HH 96
#define WW 96
#define CC 21
#define BB 2
#define NN (HH*WW)          // 9216
#define NT16 (NN/16)        // 576 sorted 16-tiles per batch
#define NJB  (NN/32)        // 288 j-blocks per batch
#define CHK 8               // kept-jblocks per worklist slot
#define NCONV (BB*CC)       // 42 conv blocks
#define NBIL 648            // bilateral blocks (2592 waves, grid-stride)
#define NUPD (BB*NN/256)    // 72 updater blocks
#define NWORKER (NCONV+NBIL)
#define PRUNE_T 24.0f       // exp2-domain skip threshold
#define GST 104             // LDS row stride for 96-wide bf16 rows

// feature pre-scale folds 1/2 and log2(e): k = exp2(-sum(diff^2))
#define KSA2 (0.84932184f / 160.0f)   // bilateral spatial
#define KSB2 (0.84932184f / 3.0f)     // bilateral color
#define GL2  (1.44269504f / 18.0f)    // spatial kernel exp(-d^2/18) in exp2 units

typedef __attribute__((ext_vector_type(4))) float f32x4;
typedef __attribute__((ext_vector_type(8))) short short8;
typedef __attribute__((ext_vector_type(4))) int int4v;

static __device__ inline unsigned pk_bf16(float a, float b) {
    unsigned ua = __builtin_bit_cast(unsigned, a);
    unsigned ub = __builtin_bit_cast(unsigned, b);
    ua += 0x7FFF + ((ua >> 16) & 1);
    ub += 0x7FFF + ((ub >> 16) & 1);
    return (ua >> 16) | (ub & 0xFFFF0000u);
}
static __device__ inline unsigned short bf16_1(float a) {
    unsigned ua = __builtin_bit_cast(unsigned, a);
    ua += 0x7FFF + ((ua >> 16) & 1);
    return (unsigned short)(ua >> 16);
}

// ---------------- P0: tables + constant smht rows + zero {hist,wlc,done} ---
__global__ __launch_bounds__(256) void prep_kernel(
    float* __restrict__ sxt, unsigned short* __restrict__ gbt,
    unsigned short* __restrict__ smht, int* __restrict__ gh,
    int* __restrict__ wlc, int* __restrict__ done)
{
    int idx = blockIdx.x * 256 + threadIdx.x;
    if (idx == 0) wlc[0] = 0;
    if (idx < 8) done[idx] = 0;
    if (idx < BB * 11 * NN) {
        int b = idx / (11 * NN);
        int rem = idx - b * 11 * NN;
        int r = rem / NN, col = rem - r * NN;
        smht[(size_t)(b * 32 + 21 + r) * NN + col] = (r == 0) ? 0x3F80 : 0;
    }
    if (idx < BB * 4096) gh[idx] = 0;
    if (blockIdx.x == 0) {
        __shared__ float gt[96];
        int t = threadIdx.x;
        if (t < 96) gt[t] = __builtin_amdgcn_exp2f(-(float)(t * t) * GL2);
        __syncthreads();
        if (t < 96) {
            float s = 0.f;
            for (int v = 0; v < 96; v++) s += gt[abs(t - v)];
            sxt[t] = s;
            for (int v = 0; v < 96; v++) gbt[t * 96 + v] = bf16_1(gt[abs(t - v)]);
        }
    }
}

// ---------------- P1: parallel counting sort by 12-bit color cell ----------
__global__ __launch_bounds__(256) void hist_kernel(
    const float* __restrict__ rgb, int* __restrict__ gh)
{
    int idx = blockIdx.x * 256 + threadIdx.x;
    if (idx >= BB * NN) return;
    int b = idx / NN;
    const float* rp = rgb + (size_t)idx * 3;
    int cr = min(15, (int)rp[0] >> 4);
    int cg = min(15, (int)rp[1] >> 4);
    int cb = min(15, (int)rp[2] >> 4);
    atomicAdd(&gh[b * 4096 + ((cr << 8) | (cg << 4) | cb)], 1);
}

__global__ __launch_bounds__(256) void scan_kernel(
    const int* __restrict__ gh, int* __restrict__ goff)
{
    __shared__ int ps[256];
    int t = threadIdx.x, b = blockIdx.x;
    int base = b * 4096 + t * 16;
    int loc[16], s = 0;
#pragma unroll
    for (int k = 0; k < 16; k++) { loc[k] = gh[base + k]; s += loc[k]; }
    ps[t] = s;
    __syncthreads();
    for (int off = 1; off < 256; off <<= 1) {
        int add = (t >= off) ? ps[t - off] : 0;
        __syncthreads();
        ps[t] += add;
        __syncthreads();
    }
    int run = ps[t] - s;
#pragma unroll
    for (int k = 0; k < 16; k++) { goff[base + k] = run; run += loc[k]; }
}

__global__ __launch_bounds__(256) void scatter_kernel(
    const float* __restrict__ rgb, int* __restrict__ goff,
    int* __restrict__ spos, float* __restrict__ fjs)
{
    int idx = blockIdx.x * 256 + threadIdx.x;
    if (idx >= BB * NN) return;
    int b = idx / NN, p = idx - b * NN;
    const float* rp = rgb + (size_t)idx * 3;
    float r = rp[0], g = rp[1], bl = rp[2];
    int cr = min(15, (int)r >> 4);
    int cg = min(15, (int)g >> 4);
    int cb = min(15, (int)bl >> 4);
    int pos = atomicAdd(&goff[b * 4096 + ((cr << 8) | (cg << 4) | cb)], 1);
    spos[idx] = pos;
    int y = p / WW, x = p - y * WW;
    float* fb = fjs + (size_t)b * 5 * NN;
    fb[0 * NN + pos] = r * KSB2;
    fb[1 * NN + pos] = g * KSB2;
    fb[2 * NN + pos] = bl * KSB2;
    fb[3 * NN + pos] = (float)y * KSA2;
    fb[4 * NN + pos] = (float)x * KSA2;
}

// ---------------- P2a: color bbox per sorted 16-tile -----------------------
__global__ __launch_bounds__(256) void bounds_kernel(
    const float* __restrict__ fjs, float* __restrict__ bnd)
{
    int idx = blockIdx.x * 256 + threadIdx.x;
    if (idx >= BB * NT16) return;
    int b = idx / NT16, tile = idx - b * NT16;
    const float* fb = fjs + (size_t)b * 5 * NN + tile * 16;
    float lo[3], hi[3];
#pragma unroll
    for (int f = 0; f < 3; f++) { lo[f] = 1e30f; hi[f] = -1e30f; }
    for (int k = 0; k < 16; k++) {
#pragma unroll
        for (int f = 0; f < 3; f++) {
            float v = fb[f * NN + k];
            lo[f] = fminf(lo[f], v); hi[f] = fmaxf(hi[f], v);
        }
    }
    float* o = bnd + (size_t)idx * 6;
#pragma unroll
    for (int f = 0; f < 3; f++) { o[2 * f] = lo[f]; o[2 * f + 1] = hi[f]; }
}

// ------ P2b: wave-parallel mask + ballot-compact jlist + emit worklist -----
__global__ __launch_bounds__(256) void maskchunks_kernel(
    const float* __restrict__ bnd, unsigned short* __restrict__ jlist,
    int* __restrict__ cnt, int* __restrict__ wl, int* __restrict__ wlc)
{
    int lane = threadIdx.x & 63;
    int bt = blockIdx.x * 4 + (threadIdx.x >> 6);
    if (bt >= BB * NT16) return;
    int b = bt / NT16;
    const float* tb = bnd + (size_t)bt * 6;
    float tlo0 = tb[0], thi0 = tb[1], tlo1 = tb[2], thi1 = tb[3], tlo2 = tb[4], thi2 = tb[5];
    unsigned short* jl = jlist + (size_t)bt * NJB;
    const float* bb = bnd + (size_t)b * NT16 * 6;
    int n = 0;
#pragma unroll
    for (int r = 0; r < 5; r++) {
        int jb = r * 64 + lane;
        bool keep = false;
        if (jb < NJB) {
            const float* a0 = bb + (size_t)(2 * jb) * 6;
            float s = 0.f;
#pragma unroll
            for (int f = 0; f < 3; f++) {
                float jlo = fminf(a0[2 * f], a0[6 + 2 * f]);
                float jhi = fmaxf(a0[2 * f + 1], a0[6 + 2 * f + 1]);
                float lo = (f == 0) ? tlo0 : (f == 1) ? tlo1 : tlo2;
                float hi = (f == 0) ? thi0 : (f == 1) ? thi1 : thi2;
                float gap = fmaxf(0.f, fmaxf(lo - jhi, jlo - hi));
                s = fmaf(gap, gap, s);
            }
            keep = (s <= PRUNE_T);
        }
        unsigned long long m = __ballot(keep);
        if (keep) {
            int pre = __popcll(m & ((1ull << lane) - 1ull));
            jl[n + pre] = (unsigned short)jb;
        }
        n += __popcll(m);
    }
    if (lane == 0) {
        cnt[bt] = n;
        int nsl = (n + CHK - 1) / CHK;
        if (nsl > 0) {
            int base = atomicAdd(wlc, nsl);
            for (int s2 = 0; s2 < nsl; s2++) wl[base + s2] = bt * 64 + s2;
        }
    }
}

// ---------------- K1: per-pixel softmax (iteration 0) ----------------------
__global__ __launch_bounds__(256) void softmax_kernel(
    const float* __restrict__ q, const int* __restrict__ spos,
    unsigned short* __restrict__ smpb, unsigned short* __restrict__ smht,
    float* __restrict__ part)
{
    int idx = blockIdx.x * 256 + threadIdx.x;
    if (idx >= BB * NN) return;
    int b = idx / NN, p = idx - b * NN;
    const float* qp = q + (size_t)idx * CC;
    float v[CC], m = -1e30f;
#pragma unroll
    for (int c = 0; c < CC; c++) { v[c] = qp[c]; m = fmaxf(m, v[c]); }
    float ssum = 0.f;
#pragma unroll
    for (int c = 0; c < CC; c++) { v[c] = __expf(v[c] - m); ssum += v[c]; }
    float inv = 1.0f / ssum;
    int s = spos[idx];
#pragma unroll
    for (int c = 0; c < CC; c++) {
        unsigned short h = bf16_1(v[c] * inv);
        smpb[(size_t)(b * CC + c) * NN + p] = h;
        smht[(size_t)(b * 32 + c) * NN + s] = h;
    }
    float* pp = part + (size_t)(b * NN + s) * 24;
#pragma unroll
    for (int k = 0; k < 24; k++) pp[k] = 0.f;
}

// ---------------- bilateral helpers (depth-2 pipelined j-set) --------------
struct JSet { float vf[5][8]; short8 sb0, sb1; };

static __device__ __forceinline__ void load_jset(
    JSet& s, const float* __restrict__ fb, const unsigned short* __restrict__ smb,
    int jb, int quad, int l16)
{
    int coff = jb * 32 + quad * 8;
#pragma unroll
    for (int f = 0; f < 5; f++) {
        const float4* pf = (const float4*)(fb + (size_t)f * NN + coff);
        float4 lo = pf[0], hi = pf[1];
        s.vf[f][0] = lo.x; s.vf[f][1] = lo.y; s.vf[f][2] = lo.z; s.vf[f][3] = lo.w;
        s.vf[f][4] = hi.x; s.vf[f][5] = hi.y; s.vf[f][6] = hi.z; s.vf[f][7] = hi.w;
    }
    s.sb0 = *(const short8*)(smb + (size_t)l16 * NN + coff);
    s.sb1 = *(const short8*)(smb + (size_t)(16 + l16) * NN + coff);
}

static __device__ __forceinline__ void compute_jset(
    const JSet& s, float fi0, float fi1, float fi2, float fi3, float fi4,
    f32x4& acc0, f32x4& acc1)
{
    float kf[8];
#pragma unroll
    for (int e = 0; e < 8; e++) {
        float d0 = s.vf[0][e] - fi0;
        float d1 = s.vf[1][e] - fi1;
        float d2 = s.vf[2][e] - fi2;
        float d3 = s.vf[3][e] - fi3;
        float d4 = s.vf[4][e] - fi4;
        float sm = d0 * d0;
        sm = fmaf(d1, d1, sm);
        sm = fmaf(d2, d2, sm);
        sm = fmaf(d3, d3, sm);
        sm = fmaf(d4, d4, sm);
        kf[e] = __builtin_amdgcn_exp2f(-sm);
    }
    int4v ap = { (int)pk_bf16(kf[0], kf[1]), (int)pk_bf16(kf[2], kf[3]),
                 (int)pk_bf16(kf[4], kf[5]), (int)pk_bf16(kf[6], kf[7]) };
    short8 afrag = __builtin_bit_cast(short8, ap);
    acc0 = __builtin_amdgcn_mfma_f32_16x16x32_bf16(afrag, s.sb0, acc0, 0, 0, 0);
    acc1 = __builtin_amdgcn_mfma_f32_16x16x32_bf16(afrag, s.sb1, acc1, 0, 0, 0);
}

// ===== K2: ONE dispatch per CRF iteration ==================================
// blocks [0,42): conv planes | [42,690): bilateral worklist | [690,762):
// updaters, spin on device-scope counter until all 690 workers release.
// All 762 blocks are co-resident (3/CU, 25KB LDS, 4 waves), so the spin is
// short; even unordered scheduling cannot deadlock (only tail blocks spin).
__global__ __launch_bounds__(256) void iter_kernel(
    const unsigned short* __restrict__ smpb, const unsigned short* __restrict__ gbt,
    const float* __restrict__ sxt, float* __restrict__ spf,
    const unsigned short* __restrict__ smht_c, const float* __restrict__ fjs,
    const unsigned short* __restrict__ jlist, const int* __restrict__ cntv,
    const int* __restrict__ wl, const int* __restrict__ wlc,
    float* __restrict__ part,
    const float* __restrict__ u, const int* __restrict__ spos,
    const float* __restrict__ Ws, const float* __restrict__ Wb,
    const float* __restrict__ M, float* __restrict__ qout,
    unsigned short* __restrict__ smpb_w, unsigned short* __restrict__ smht_w,
    int* __restrict__ done, int wr)
{
    __shared__ unsigned short C1t[96 * GST];     // conv transpose / reuse below
    int tid = threadIdx.x;
    int lane = tid & 63, w = tid >> 6;
    int quad = lane >> 4, l16 = lane & 15;
    int bid = blockIdx.x;

    if (bid < NCONV) {
        // ================= conv role: SP = G @ P @ G =================
        const unsigned short* plane = smpb + (size_t)bid * NN;
        for (int mt = w; mt < 6; mt += 4) {
            int m0 = mt * 16;
            short8 a[3];
#pragma unroll
            for (int kk = 0; kk < 3; kk++)
                a[kk] = *(const short8*)(plane + (size_t)(m0 + l16) * 96 + kk * 32 + quad * 8);
            f32x4 acc[6];
#pragma unroll
            for (int nt = 0; nt < 6; nt++) acc[nt] = (f32x4){0.f, 0.f, 0.f, 0.f};
#pragma unroll
            for (int nt = 0; nt < 6; nt++) {
#pragma unroll
                for (int kk = 0; kk < 3; kk++) {
                    short8 bf = *(const short8*)(gbt + (nt * 16 + l16) * 96 + kk * 32 + quad * 8);
                    acc[nt] = __builtin_amdgcn_mfma_f32_16x16x32_bf16(a[kk], bf, acc[nt], 0, 0, 0);
                }
            }
#pragma unroll
            for (int nt = 0; nt < 6; nt++) {
                unsigned* dst = (unsigned*)&C1t[(nt * 16 + l16) * GST + m0 + quad * 4];
                dst[0] = pk_bf16(acc[nt][0], acc[nt][1]);
                dst[1] = pk_bf16(acc[nt][2], acc[nt][3]);
            }
        }
        __syncthreads();
        float* outp = spf + (size_t)bid * NN;
        for (int mt = w; mt < 6; mt += 4) {
            int m0 = mt * 16;
            short8 a[3];
#pragma unroll
            for (int kk = 0; kk < 3; kk++)
                a[kk] = *(const short8*)(gbt + (m0 + l16) * 96 + kk * 32 + quad * 8);
            f32x4 acc[6];
#pragma unroll
            for (int nt = 0; nt < 6; nt++) acc[nt] = (f32x4){0.f, 0.f, 0.f, 0.f};
#pragma unroll
            for (int nt = 0; nt < 6; nt++) {
#pragma unroll
                for (int kk = 0; kk < 3; kk++) {
                    short8 bf = *(const short8*)&C1t[(nt * 16 + l16) * GST + kk * 32 + quad * 8];
                    acc[nt] = __builtin_amdgcn_mfma_f32_16x16x32_bf16(a[kk], bf, acc[nt], 0, 0, 0);
                }
            }
#pragma unroll
            for (int nt = 0; nt < 6; nt++) {
                int x = nt * 16 + l16;
                float sx = sxt[x];
#pragma unroll
                for (int r = 0; r < 4; r++) {
                    int y = m0 + quad * 4 + r;
                    float invn = __builtin_amdgcn_rcpf(sxt[y] * sx);
                    outp[y * 96 + x] = acc[nt][r] * invn;
                }
            }
        }
    } else if (bid < NWORKER) {
        // ================= bilateral role: worklist grid-stride =================
        int nwl = wlc[0];
        for (int widx = (bid - NCONV) * 4 + w; widx < nwl; widx += NBIL * 4) {
            int e = wl[widx];
            int bt = e >> 6, ck = e & 63;
            int cnt = min(cntv[bt] - ck * CHK, CHK);
            int b = bt / NT16, tile16 = bt - b * NT16;
            int i = tile16 * 16 + l16;
            const float* fb = fjs + (size_t)b * 5 * NN;
            float fi0 = fb[0 * NN + i], fi1 = fb[1 * NN + i], fi2 = fb[2 * NN + i];
            float fi3 = fb[3 * NN + i], fi4 = fb[4 * NN + i];
            f32x4 acc0 = {0.f, 0.f, 0.f, 0.f};
            f32x4 acc1 = {0.f, 0.f, 0.f, 0.f};
            const unsigned short* smb = smht_c + (size_t)b * 32 * NN;
            const unsigned short* jl = jlist + (size_t)bt * NJB + ck * CHK;
            JSet A, B;
            load_jset(A, fb, smb, jl[0], quad, l16);
            int k = 0;
            while (true) {
                if (k + 1 < cnt) load_jset(B, fb, smb, jl[k + 1], quad, l16);
                compute_jset(A, fi0, fi1, fi2, fi3, fi4, acc0, acc1);
                if (++k >= cnt) break;
                if (k + 1 < cnt) load_jset(A, fb, smb, jl[k + 1], quad, l16);
                compute_jset(B, fi0, fi1, fi2, fi3, fi4, acc0, acc1);
                if (++k >= cnt) break;
            }
            int ibase = tile16 * 16 + quad * 4;
            float* pr = part + (size_t)b * NN * 24;
#pragma unroll
            for (int r = 0; r < 4; r++)
                atomicAdd(&pr[(size_t)(ibase + r) * 24 + l16], acc0[r]);
            if (l16 < 6) {
#pragma unroll
                for (int r = 0; r < 4; r++)
                    atomicAdd(&pr[(size_t)(ibase + r) * 24 + 16 + l16], acc1[r]);
            }
        }
    }

    if (bid < NWORKER) {
        // worker epilogue: publish stores, then release-increment
        __threadfence();
        __syncthreads();
        if (tid == 0)
            __hip_atomic_fetch_add(done, 1, __ATOMIC_RELEASE, __HIP_MEMORY_SCOPE_AGENT);
        return;
    }

    // ================= updater role =================
    if (tid == 0) {
        while (__hip_atomic_load(done, __ATOMIC_ACQUIRE, __HIP_MEMORY_SCOPE_AGENT) < NWORKER)
            __builtin_amdgcn_s_sleep(8);
    }
    __syncthreads();
    __threadfence();

    float* sWs = (float*)&C1t[0];
    float* sWb = sWs + 441;
    float* sM  = sWb + 441;
    for (int t = tid; t < 441; t += 256) { sWs[t] = Ws[t]; sWb[t] = Wb[t]; sM[t] = M[t]; }
    __syncthreads();

    int idx = (bid - NWORKER) * 256 + tid;
    int b = idx / NN, p = idx - b * NN;
    int s = spos[idx];
    float* pp = part + (size_t)(b * NN + s) * 24;
    float blv[22];
#pragma unroll
    for (int c = 0; c < 22; c++) blv[c] = pp[c];
    float ninv = 1.0f / blv[21];
    float spv[CC], msg[CC];
#pragma unroll
    for (int c = 0; c < CC; c++) {
        blv[c] *= ninv;
        spv[c] = spf[(size_t)(b * CC + c) * NN + p];
    }
#pragma unroll
    for (int c = 0; c < CC; c++) {
        float a = 0.f;
        const float* wr2 = &sWs[c * CC];
        const float* br = &sWb[c * CC];
#pragma unroll
        for (int c2 = 0; c2 < CC; c2++) a = fmaf(wr2[c2], spv[c2], a);
#pragma unroll
        for (int c2 = 0; c2 < CC; c2++) a = fmaf(br[c2], blv[c2], a);
        msg[c] = a;
    }
    const float* up = u + (size_t)idx * CC;
    float* qp = qout + (size_t)idx * CC;
    float qv[CC];
#pragma unroll
    for (int c = 0; c < CC; c++) {
        float a = up[c];
        const float* mr = &sM[c * CC];
#pragma unroll
        for (int c2 = 0; c2 < CC; c2++) a = fmaf(-mr[c2], msg[c2], a);
        qv[c] = a;
        qp[c] = a;
    }
    if (wr) {
        float m = -1e30f;
#pragma unroll
        for (int c = 0; c < CC; c++) m = fmaxf(m, qv[c]);
        float ssum = 0.f;
#pragma unroll
        for (int c = 0; c < CC; c++) { qv[c] = __expf(qv[c] - m); ssum += qv[c]; }
        float inv = 1.0f / ssum;
#pragma unroll
        for (int c = 0; c < CC; c++) {
            unsigned short h = bf16_1(qv[c] * inv);
            smpb_w[(size_t)(b * CC + c) * NN + p] = h;
            smht_w[(size_t)(b * 32 + c) * NN + s] = h;
        }
#pragma unroll
        for (int k = 0; k < 24; k++) pp[k] = 0.f;
    }
}

extern "C" void kernel_launch(void* const* d_in, const int* in_sizes, int n_in,
                              void* d_out, int out_size, void* d_ws, size_t ws_size,
                              hipStream_t stream)
{
    const float* unary = (const float*)d_in[0];  // [B,H,W,C]
    const float* rgb   = (const float*)d_in[1];  // [B,H,W,3]
    const float* Ws    = (const float*)d_in[2];
    const float* Wb    = (const float*)d_in[3];
    const float* M     = (const float*)d_in[4];
    float* out = (float*)d_out;                  // [B,N,C]

    float* SXT  = (float*)d_ws;                            // 96
    float* FJS  = SXT + 96;                                // B*5*N
    float* SPF  = FJS + (size_t)BB * 5 * NN;               // B*21*N
    float* PART = SPF + (size_t)BB * CC * NN;              // B*N*24
    float* BND  = PART + (size_t)BB * NN * 24;             // B*576*6
    int*   SPOS = (int*)(BND + (size_t)BB * NT16 * 6);     // B*N
    int*   GH   = SPOS + BB * NN;                          // B*4096
    int*   GOFF = GH + BB * 4096;                          // B*4096
    int*   CNT  = GOFF + BB * 4096;                        // B*576
    int*   WLC  = CNT + BB * NT16;                         // 1
    int*   DONE = WLC + 1;                                 // 8
    int*   WL   = DONE + 8;                                // <= B*576*36
    unsigned short* JL = (unsigned short*)(WL + BB * NT16 * 36);  // B*576*288
    unsigned short* SMHT = JL + (size_t)BB * NT16 * NJB;   // B*32*N
    unsigned short* SMPB = SMHT + (size_t)BB * 32 * NN;    // B*21*N
    unsigned short* GBT  = SMPB + (size_t)BB * CC * NN;    // 96*96

    prep_kernel<<<(BB * 11 * NN + 255) / 256, 256, 0, stream>>>(SXT, GBT, SMHT, GH, WLC, DONE);
    hist_kernel<<<(BB * NN + 255) / 256, 256, 0, stream>>>(rgb, GH);
    scan_kernel<<<BB, 256, 0, stream>>>(GH, GOFF);
    scatter_kernel<<<(BB * NN + 255) / 256, 256, 0, stream>>>(rgb, GOFF, SPOS, FJS);
    bounds_kernel<<<(BB * NT16 + 255) / 256, 256, 0, stream>>>(FJS, BND);
    maskchunks_kernel<<<(BB * NT16 + 3) / 4, 256, 0, stream>>>(BND, JL, CNT, WL, WLC);

    softmax_kernel<<<(BB * NN + 255) / 256, 256, 0, stream>>>(unary, SPOS, SMPB, SMHT, PART);
    for (int it = 0; it < 5; ++it) {
        iter_kernel<<<NWORKER + NUPD, 256, 0, stream>>>(
            SMPB, GBT, SXT, SPF, SMHT, FJS, JL, CNT, WL, WLC, PART,
            unary, SPOS, Ws, Wb, M, out, SMPB, SMHT, DONE + it, (it < 4) ? 1 : 0);
    }
}

// Round 9
// 449.011 us; speedup vs baseline: 1.5814x; 1.5814x over previous
//
#include <hip/hip_runtime.h>

#define HH 96
#define WW 96
#define CC 21
#define BB 2
#define NN (HH*WW)          // 9216
#define NT16 (NN/16)        // 576 sorted 16-tiles per batch
#define NJB  (NN/32)        // 288 j-blocks per batch
#define CHK 8               // kept-jblocks per worklist slot
#define NCONV (BB*CC)       // 42 conv blocks
#define NBIL 648            // bilateral blocks (2592 waves, grid-stride)
#define NUPD (BB*NN/256)    // 72 updater blocks
#define NWORKER (NCONV+NBIL)
#define PRUNE_T 24.0f       // exp2-domain skip threshold
#define GST 104             // LDS row stride for 96-wide bf16 rows

// feature pre-scale folds 1/2 and log2(e): k = exp2(-sum(diff^2))
#define KSA2 (0.84932184f / 160.0f)   // bilateral spatial
#define KSB2 (0.84932184f / 3.0f)     // bilateral color
#define GL2  (1.44269504f / 18.0f)    // spatial kernel exp(-d^2/18) in exp2 units

typedef __attribute__((ext_vector_type(4))) float f32x4;
typedef __attribute__((ext_vector_type(8))) short short8;
typedef __attribute__((ext_vector_type(4))) int int4v;

static __device__ inline unsigned pk_bf16(float a, float b) {
    unsigned ua = __builtin_bit_cast(unsigned, a);
    unsigned ub = __builtin_bit_cast(unsigned, b);
    ua += 0x7FFF + ((ua >> 16) & 1);
    ub += 0x7FFF + ((ub >> 16) & 1);
    return (ua >> 16) | (ub & 0xFFFF0000u);
}
static __device__ inline unsigned short bf16_1(float a) {
    unsigned ua = __builtin_bit_cast(unsigned, a);
    ua += 0x7FFF + ((ua >> 16) & 1);
    return (unsigned short)(ua >> 16);
}

// ---------------- P0: tables + constant smht rows + zero {hist,wlc,done} ---
__global__ __launch_bounds__(256) void prep_kernel(
    float* __restrict__ sxt, unsigned short* __restrict__ gbt,
    unsigned short* __restrict__ smht, int* __restrict__ gh,
    int* __restrict__ wlc, int* __restrict__ done)
{
    int idx = blockIdx.x * 256 + threadIdx.x;
    if (idx == 0) wlc[0] = 0;
    if (idx < 8) done[idx] = 0;
    if (idx < BB * 11 * NN) {
        int b = idx / (11 * NN);
        int rem = idx - b * 11 * NN;
        int r = rem / NN, col = rem - r * NN;
        smht[(size_t)(b * 32 + 21 + r) * NN + col] = (r == 0) ? 0x3F80 : 0;
    }
    if (idx < BB * 4096) gh[idx] = 0;
    if (blockIdx.x == 0) {
        __shared__ float gt[96];
        int t = threadIdx.x;
        if (t < 96) gt[t] = __builtin_amdgcn_exp2f(-(float)(t * t) * GL2);
        __syncthreads();
        if (t < 96) {
            float s = 0.f;
            for (int v = 0; v < 96; v++) s += gt[abs(t - v)];
            sxt[t] = s;
            for (int v = 0; v < 96; v++) gbt[t * 96 + v] = bf16_1(gt[abs(t - v)]);
        }
    }
}

// ---------------- P1: parallel counting sort by 12-bit color cell ----------
__global__ __launch_bounds__(256) void hist_kernel(
    const float* __restrict__ rgb, int* __restrict__ gh)
{
    int idx = blockIdx.x * 256 + threadIdx.x;
    if (idx >= BB * NN) return;
    int b = idx / NN;
    const float* rp = rgb + (size_t)idx * 3;
    int cr = min(15, (int)rp[0] >> 4);
    int cg = min(15, (int)rp[1] >> 4);
    int cb = min(15, (int)rp[2] >> 4);
    atomicAdd(&gh[b * 4096 + ((cr << 8) | (cg << 4) | cb)], 1);
}

__global__ __launch_bounds__(256) void scan_kernel(
    const int* __restrict__ gh, int* __restrict__ goff)
{
    __shared__ int ps[256];
    int t = threadIdx.x, b = blockIdx.x;
    int base = b * 4096 + t * 16;
    int loc[16], s = 0;
#pragma unroll
    for (int k = 0; k < 16; k++) { loc[k] = gh[base + k]; s += loc[k]; }
    ps[t] = s;
    __syncthreads();
    for (int off = 1; off < 256; off <<= 1) {
        int add = (t >= off) ? ps[t - off] : 0;
        __syncthreads();
        ps[t] += add;
        __syncthreads();
    }
    int run = ps[t] - s;
#pragma unroll
    for (int k = 0; k < 16; k++) { goff[base + k] = run; run += loc[k]; }
}

__global__ __launch_bounds__(256) void scatter_kernel(
    const float* __restrict__ rgb, int* __restrict__ goff,
    int* __restrict__ spos, float* __restrict__ fjs)
{
    int idx = blockIdx.x * 256 + threadIdx.x;
    if (idx >= BB * NN) return;
    int b = idx / NN, p = idx - b * NN;
    const float* rp = rgb + (size_t)idx * 3;
    float r = rp[0], g = rp[1], bl = rp[2];
    int cr = min(15, (int)r >> 4);
    int cg = min(15, (int)g >> 4);
    int cb = min(15, (int)bl >> 4);
    int pos = atomicAdd(&goff[b * 4096 + ((cr << 8) | (cg << 4) | cb)], 1);
    spos[idx] = pos;
    int y = p / WW, x = p - y * WW;
    float* fb = fjs + (size_t)b * 5 * NN;
    fb[0 * NN + pos] = r * KSB2;
    fb[1 * NN + pos] = g * KSB2;
    fb[2 * NN + pos] = bl * KSB2;
    fb[3 * NN + pos] = (float)y * KSA2;
    fb[4 * NN + pos] = (float)x * KSA2;
}

// ---------------- P2a: color bbox per sorted 16-tile -----------------------
__global__ __launch_bounds__(256) void bounds_kernel(
    const float* __restrict__ fjs, float* __restrict__ bnd)
{
    int idx = blockIdx.x * 256 + threadIdx.x;
    if (idx >= BB * NT16) return;
    int b = idx / NT16, tile = idx - b * NT16;
    const float* fb = fjs + (size_t)b * 5 * NN + tile * 16;
    float lo[3], hi[3];
#pragma unroll
    for (int f = 0; f < 3; f++) { lo[f] = 1e30f; hi[f] = -1e30f; }
    for (int k = 0; k < 16; k++) {
#pragma unroll
        for (int f = 0; f < 3; f++) {
            float v = fb[f * NN + k];
            lo[f] = fminf(lo[f], v); hi[f] = fmaxf(hi[f], v);
        }
    }
    float* o = bnd + (size_t)idx * 6;
#pragma unroll
    for (int f = 0; f < 3; f++) { o[2 * f] = lo[f]; o[2 * f + 1] = hi[f]; }
}

// ------ P2b: wave-parallel mask + ballot-compact jlist + emit worklist -----
__global__ __launch_bounds__(256) void maskchunks_kernel(
    const float* __restrict__ bnd, unsigned short* __restrict__ jlist,
    int* __restrict__ cnt, int* __restrict__ wl, int* __restrict__ wlc)
{
    int lane = threadIdx.x & 63;
    int bt = blockIdx.x * 4 + (threadIdx.x >> 6);
    if (bt >= BB * NT16) return;
    int b = bt / NT16;
    const float* tb = bnd + (size_t)bt * 6;
    float tlo0 = tb[0], thi0 = tb[1], tlo1 = tb[2], thi1 = tb[3], tlo2 = tb[4], thi2 = tb[5];
    unsigned short* jl = jlist + (size_t)bt * NJB;
    const float* bb = bnd + (size_t)b * NT16 * 6;
    int n = 0;
#pragma unroll
    for (int r = 0; r < 5; r++) {
        int jb = r * 64 + lane;
        bool keep = false;
        if (jb < NJB) {
            const float* a0 = bb + (size_t)(2 * jb) * 6;
            float s = 0.f;
#pragma unroll
            for (int f = 0; f < 3; f++) {
                float jlo = fminf(a0[2 * f], a0[6 + 2 * f]);
                float jhi = fmaxf(a0[2 * f + 1], a0[6 + 2 * f + 1]);
                float lo = (f == 0) ? tlo0 : (f == 1) ? tlo1 : tlo2;
                float hi = (f == 0) ? thi0 : (f == 1) ? thi1 : thi2;
                float gap = fmaxf(0.f, fmaxf(lo - jhi, jlo - hi));
                s = fmaf(gap, gap, s);
            }
            keep = (s <= PRUNE_T);
        }
        unsigned long long m = __ballot(keep);
        if (keep) {
            int pre = __popcll(m & ((1ull << lane) - 1ull));
            jl[n + pre] = (unsigned short)jb;
        }
        n += __popcll(m);
    }
    if (lane == 0) {
        cnt[bt] = n;
        int nsl = (n + CHK - 1) / CHK;
        if (nsl > 0) {
            int base = atomicAdd(wlc, nsl);
            for (int s2 = 0; s2 < nsl; s2++) wl[base + s2] = bt * 64 + s2;
        }
    }
}

// ---------------- K1: per-pixel softmax (iteration 0) ----------------------
__global__ __launch_bounds__(256) void softmax_kernel(
    const float* __restrict__ q, const int* __restrict__ spos,
    unsigned short* __restrict__ smpb, unsigned short* __restrict__ smht,
    float* __restrict__ part)
{
    int idx = blockIdx.x * 256 + threadIdx.x;
    if (idx >= BB * NN) return;
    int b = idx / NN, p = idx - b * NN;
    const float* qp = q + (size_t)idx * CC;
    float v[CC], m = -1e30f;
#pragma unroll
    for (int c = 0; c < CC; c++) { v[c] = qp[c]; m = fmaxf(m, v[c]); }
    float ssum = 0.f;
#pragma unroll
    for (int c = 0; c < CC; c++) { v[c] = __expf(v[c] - m); ssum += v[c]; }
    float inv = 1.0f / ssum;
    int s = spos[idx];
#pragma unroll
    for (int c = 0; c < CC; c++) {
        unsigned short h = bf16_1(v[c] * inv);
        smpb[(size_t)(b * CC + c) * NN + p] = h;
        smht[(size_t)(b * 32 + c) * NN + s] = h;
    }
    float* pp = part + (size_t)(b * NN + s) * 24;
#pragma unroll
    for (int k = 0; k < 24; k++) pp[k] = 0.f;
}

// ---------------- bilateral helpers (depth-2 pipelined j-set) --------------
struct JSet { float vf[5][8]; short8 sb0, sb1; };

static __device__ __forceinline__ void load_jset(
    JSet& s, const float* __restrict__ fb, const unsigned short* __restrict__ smb,
    int jb, int quad, int l16)
{
    int coff = jb * 32 + quad * 8;
#pragma unroll
    for (int f = 0; f < 5; f++) {
        const float4* pf = (const float4*)(fb + (size_t)f * NN + coff);
        float4 lo = pf[0], hi = pf[1];
        s.vf[f][0] = lo.x; s.vf[f][1] = lo.y; s.vf[f][2] = lo.z; s.vf[f][3] = lo.w;
        s.vf[f][4] = hi.x; s.vf[f][5] = hi.y; s.vf[f][6] = hi.z; s.vf[f][7] = hi.w;
    }
    s.sb0 = *(const short8*)(smb + (size_t)l16 * NN + coff);
    s.sb1 = *(const short8*)(smb + (size_t)(16 + l16) * NN + coff);
}

static __device__ __forceinline__ void compute_jset(
    const JSet& s, float fi0, float fi1, float fi2, float fi3, float fi4,
    f32x4& acc0, f32x4& acc1)
{
    float kf[8];
#pragma unroll
    for (int e = 0; e < 8; e++) {
        float d0 = s.vf[0][e] - fi0;
        float d1 = s.vf[1][e] - fi1;
        float d2 = s.vf[2][e] - fi2;
        float d3 = s.vf[3][e] - fi3;
        float d4 = s.vf[4][e] - fi4;
        float sm = d0 * d0;
        sm = fmaf(d1, d1, sm);
        sm = fmaf(d2, d2, sm);
        sm = fmaf(d3, d3, sm);
        sm = fmaf(d4, d4, sm);
        kf[e] = __builtin_amdgcn_exp2f(-sm);
    }
    int4v ap = { (int)pk_bf16(kf[0], kf[1]), (int)pk_bf16(kf[2], kf[3]),
                 (int)pk_bf16(kf[4], kf[5]), (int)pk_bf16(kf[6], kf[7]) };
    short8 afrag = __builtin_bit_cast(short8, ap);
    acc0 = __builtin_amdgcn_mfma_f32_16x16x32_bf16(afrag, s.sb0, acc0, 0, 0, 0);
    acc1 = __builtin_amdgcn_mfma_f32_16x16x32_bf16(afrag, s.sb1, acc1, 0, 0, 0);
}

// ===== K2: ONE dispatch per CRF iteration ==================================
// blocks [0,42): conv | [42,690): bilateral worklist | [690,762): updaters.
// Sync fix vs R8: ONE fence per block, not per thread; release-writeback only
// for conv blocks (bilateral's PART writes are device-scope atomics, already
// coherent); updaters spin with RELAXED loads (no cache ops), then one
// acquire fence. 762 blocks all co-resident (<=20KB LDS => 8/CU by LDS).
__global__ __launch_bounds__(256) void iter_kernel(
    const unsigned short* __restrict__ smpb, const unsigned short* __restrict__ gbt,
    const float* __restrict__ sxt, float* __restrict__ spf,
    const unsigned short* __restrict__ smht_c, const float* __restrict__ fjs,
    const unsigned short* __restrict__ jlist, const int* __restrict__ cntv,
    const int* __restrict__ wl, const int* __restrict__ wlc,
    float* __restrict__ part,
    const float* __restrict__ u, const int* __restrict__ spos,
    const float* __restrict__ Ws, const float* __restrict__ Wb,
    const float* __restrict__ M, float* __restrict__ qout,
    unsigned short* __restrict__ smpb_w, unsigned short* __restrict__ smht_w,
    int* __restrict__ done, int wr)
{
    __shared__ unsigned short C1t[96 * GST];     // conv transpose / updater weights
    int tid = threadIdx.x;
    int lane = tid & 63, w = tid >> 6;
    int quad = lane >> 4, l16 = lane & 15;
    int bid = blockIdx.x;

    if (bid < NCONV) {
        // ================= conv role: SP = G @ P @ G =================
        const unsigned short* plane = smpb + (size_t)bid * NN;
        for (int mt = w; mt < 6; mt += 4) {
            int m0 = mt * 16;
            short8 a[3];
#pragma unroll
            for (int kk = 0; kk < 3; kk++)
                a[kk] = *(const short8*)(plane + (size_t)(m0 + l16) * 96 + kk * 32 + quad * 8);
            f32x4 acc[6];
#pragma unroll
            for (int nt = 0; nt < 6; nt++) acc[nt] = (f32x4){0.f, 0.f, 0.f, 0.f};
#pragma unroll
            for (int nt = 0; nt < 6; nt++) {
#pragma unroll
                for (int kk = 0; kk < 3; kk++) {
                    short8 bf = *(const short8*)(gbt + (nt * 16 + l16) * 96 + kk * 32 + quad * 8);
                    acc[nt] = __builtin_amdgcn_mfma_f32_16x16x32_bf16(a[kk], bf, acc[nt], 0, 0, 0);
                }
            }
#pragma unroll
            for (int nt = 0; nt < 6; nt++) {
                unsigned* dst = (unsigned*)&C1t[(nt * 16 + l16) * GST + m0 + quad * 4];
                dst[0] = pk_bf16(acc[nt][0], acc[nt][1]);
                dst[1] = pk_bf16(acc[nt][2], acc[nt][3]);
            }
        }
        __syncthreads();
        float* outp = spf + (size_t)bid * NN;
        for (int mt = w; mt < 6; mt += 4) {
            int m0 = mt * 16;
            short8 a[3];
#pragma unroll
            for (int kk = 0; kk < 3; kk++)
                a[kk] = *(const short8*)(gbt + (m0 + l16) * 96 + kk * 32 + quad * 8);
            f32x4 acc[6];
#pragma unroll
            for (int nt = 0; nt < 6; nt++) acc[nt] = (f32x4){0.f, 0.f, 0.f, 0.f};
#pragma unroll
            for (int nt = 0; nt < 6; nt++) {
#pragma unroll
                for (int kk = 0; kk < 3; kk++) {
                    short8 bf = *(const short8*)&C1t[(nt * 16 + l16) * GST + kk * 32 + quad * 8];
                    acc[nt] = __builtin_amdgcn_mfma_f32_16x16x32_bf16(a[kk], bf, acc[nt], 0, 0, 0);
                }
            }
#pragma unroll
            for (int nt = 0; nt < 6; nt++) {
                int x = nt * 16 + l16;
                float sx = sxt[x];
#pragma unroll
                for (int r = 0; r < 4; r++) {
                    int y = m0 + quad * 4 + r;
                    float invn = __builtin_amdgcn_rcpf(sxt[y] * sx);
                    outp[y * 96 + x] = acc[nt][r] * invn;
                }
            }
        }
        // release: block stores drained by barrier; ONE L2 writeback publishes them
        __syncthreads();
        if (tid == 0) {
            __threadfence();
            __hip_atomic_fetch_add(done, 1, __ATOMIC_RELAXED, __HIP_MEMORY_SCOPE_AGENT);
        }
        return;
    } else if (bid < NWORKER) {
        // ================= bilateral role: worklist grid-stride =================
        int nwl = wlc[0];
        for (int widx = (bid - NCONV) * 4 + w; widx < nwl; widx += NBIL * 4) {
            int e = wl[widx];
            int bt = e >> 6, ck = e & 63;
            int cnt = min(cntv[bt] - ck * CHK, CHK);
            int b = bt / NT16, tile16 = bt - b * NT16;
            int i = tile16 * 16 + l16;
            const float* fb = fjs + (size_t)b * 5 * NN;
            float fi0 = fb[0 * NN + i], fi1 = fb[1 * NN + i], fi2 = fb[2 * NN + i];
            float fi3 = fb[3 * NN + i], fi4 = fb[4 * NN + i];
            f32x4 acc0 = {0.f, 0.f, 0.f, 0.f};
            f32x4 acc1 = {0.f, 0.f, 0.f, 0.f};
            const unsigned short* smb = smht_c + (size_t)b * 32 * NN;
            const unsigned short* jl = jlist + (size_t)bt * NJB + ck * CHK;
            JSet A, B;
            load_jset(A, fb, smb, jl[0], quad, l16);
            int k = 0;
            while (true) {
                if (k + 1 < cnt) load_jset(B, fb, smb, jl[k + 1], quad, l16);
                compute_jset(A, fi0, fi1, fi2, fi3, fi4, acc0, acc1);
                if (++k >= cnt) break;
                if (k + 1 < cnt) load_jset(A, fb, smb, jl[k + 1], quad, l16);
                compute_jset(B, fi0, fi1, fi2, fi3, fi4, acc0, acc1);
                if (++k >= cnt) break;
            }
            int ibase = tile16 * 16 + quad * 4;
            float* pr = part + (size_t)b * NN * 24;
#pragma unroll
            for (int r = 0; r < 4; r++)
                atomicAdd(&pr[(size_t)(ibase + r) * 24 + l16], acc0[r]);
            if (l16 < 6) {
#pragma unroll
                for (int r = 0; r < 4; r++)
                    atomicAdd(&pr[(size_t)(ibase + r) * 24 + 16 + l16], acc1[r]);
            }
        }
        // release: atomics are already at the device coherent point; barrier
        // (vmcnt drain) orders them before the relaxed done-increment
        __syncthreads();
        if (tid == 0)
            __hip_atomic_fetch_add(done, 1, __ATOMIC_RELAXED, __HIP_MEMORY_SCOPE_AGENT);
        return;
    }

    // ================= updater role =================
    if (tid == 0) {
        // RELAXED spin (reads coherent point, no per-poll cache invalidate)
        while (__hip_atomic_load(done, __ATOMIC_RELAXED, __HIP_MEMORY_SCOPE_AGENT) < NWORKER)
            __builtin_amdgcn_s_sleep(8);
        __threadfence();   // single acquire: invalidate local caches once
    }
    __syncthreads();

    float* sWs = (float*)&C1t[0];
    float* sWb = sWs + 441;
    float* sM  = sWb + 441;
    for (int t = tid; t < 441; t += 256) { sWs[t] = Ws[t]; sWb[t] = Wb[t]; sM[t] = M[t]; }
    __syncthreads();

    int idx = (bid - NWORKER) * 256 + tid;
    int b = idx / NN, p = idx - b * NN;
    int s = spos[idx];
    float* pp = part + (size_t)(b * NN + s) * 24;
    float blv[22];
#pragma unroll
    for (int c = 0; c < 22; c++) blv[c] = pp[c];
    float ninv = 1.0f / blv[21];
    float spv[CC], msg[CC];
#pragma unroll
    for (int c = 0; c < CC; c++) {
        blv[c] *= ninv;
        spv[c] = spf[(size_t)(b * CC + c) * NN + p];
    }
#pragma unroll
    for (int c = 0; c < CC; c++) {
        float a = 0.f;
        const float* wr2 = &sWs[c * CC];
        const float* br = &sWb[c * CC];
#pragma unroll
        for (int c2 = 0; c2 < CC; c2++) a = fmaf(wr2[c2], spv[c2], a);
#pragma unroll
        for (int c2 = 0; c2 < CC; c2++) a = fmaf(br[c2], blv[c2], a);
        msg[c] = a;
    }
    const float* up = u + (size_t)idx * CC;
    float* qp = qout + (size_t)idx * CC;
    float qv[CC];
#pragma unroll
    for (int c = 0; c < CC; c++) {
        float a = up[c];
        const float* mr = &sM[c * CC];
#pragma unroll
        for (int c2 = 0; c2 < CC; c2++) a = fmaf(-mr[c2], msg[c2], a);
        qv[c] = a;
        qp[c] = a;
    }
    if (wr) {
        float m = -1e30f;
#pragma unroll
        for (int c = 0; c < CC; c++) m = fmaxf(m, qv[c]);
        float ssum = 0.f;
#pragma unroll
        for (int c = 0; c < CC; c++) { qv[c] = __expf(qv[c] - m); ssum += qv[c]; }
        float inv = 1.0f / ssum;
#pragma unroll
        for (int c = 0; c < CC; c++) {
            unsigned short h = bf16_1(qv[c] * inv);
            smpb_w[(size_t)(b * CC + c) * NN + p] = h;
            smht_w[(size_t)(b * 32 + c) * NN + s] = h;
        }
#pragma unroll
        for (int k = 0; k < 24; k++) pp[k] = 0.f;
    }
}

extern "C" void kernel_launch(void* const* d_in, const int* in_sizes, int n_in,
                              void* d_out, int out_size, void* d_ws, size_t ws_size,
                              hipStream_t stream)
{
    const float* unary = (const float*)d_in[0];  // [B,H,W,C]
    const float* rgb   = (const float*)d_in[1];  // [B,H,W,3]
    const float* Ws    = (const float*)d_in[2];
    const float* Wb    = (const float*)d_in[3];
    const float* M     = (const float*)d_in[4];
    float* out = (float*)d_out;                  // [B,N,C]

    float* SXT  = (float*)d_ws;                            // 96
    float* FJS  = SXT + 96;                                // B*5*N
    float* SPF  = FJS + (size_t)BB * 5 * NN;               // B*21*N
    float* PART = SPF + (size_t)BB * CC * NN;              // B*N*24
    float* BND  = PART + (size_t)BB * NN * 24;             // B*576*6
    int*   SPOS = (int*)(BND + (size_t)BB * NT16 * 6);     // B*N
    int*   GH   = SPOS + BB * NN;                          // B*4096
    int*   GOFF = GH + BB * 4096;                          // B*4096
    int*   CNT  = GOFF + BB * 4096;                        // B*576
    int*   WLC  = CNT + BB * NT16;                         // 1
    int*   DONE = WLC + 1;                                 // 8
    int*   WL   = DONE + 8;                                // <= B*576*36
    unsigned short* JL = (unsigned short*)(WL + BB * NT16 * 36);  // B*576*288
    unsigned short* SMHT = JL + (size_t)BB * NT16 * NJB;   // B*32*N
    unsigned short* SMPB = SMHT + (size_t)BB * 32 * NN;    // B*21*N
    unsigned short* GBT  = SMPB + (size_t)BB * CC * NN;    // 96*96

    prep_kernel<<<(BB * 11 * NN + 255) / 256, 256, 0, stream>>>(SXT, GBT, SMHT, GH, WLC, DONE);
    hist_kernel<<<(BB * NN + 255) / 256, 256, 0, stream>>>(rgb, GH);
    scan_kernel<<<BB, 256, 0, stream>>>(GH, GOFF);
    scatter_kernel<<<(BB * NN + 255) / 256, 256, 0, stream>>>(rgb, GOFF, SPOS, FJS);
    bounds_kernel<<<(BB * NT16 + 255) / 256, 256, 0, stream>>>(FJS, BND);
    maskchunks_kernel<<<(BB * NT16 + 3) / 4, 256, 0, stream>>>(BND, JL, CNT, WL, WLC);

    softmax_kernel<<<(BB * NN + 255) / 256, 256, 0, stream>>>(unary, SPOS, SMPB, SMHT, PART);
    for (int it = 0; it < 5; ++it) {
        iter_kernel<<<NWORKER + NUPD, 256, 0, stream>>>(
            SMPB, GBT, SXT, SPF, SMHT, FJS, JL, CNT, WL, WLC, PART,
            unary, SPOS, Ws, Wb, M, out, SMPB, SMHT, DONE + it, (it < 4) ? 1 : 0);
    }
}

// Round 10
// 315.613 us; speedup vs baseline: 2.2498x; 1.4227x over previous
//
#include <hip/hip_runtime.h>

#define HH 96
#define WW 96
#define CC 21
#define BB 2
#define NN (HH*WW)          // 9216
#define NT16 (NN/16)        // 576 sorted 16-tiles per batch
#define NJB  (NN/32)        // 288 j-blocks per batch
#define CHK 8               // kept-jblocks per worklist slot
#define NCONV (BB*CC)       // 42 conv blocks
#define NBIL 648            // bilateral blocks (2592 waves, grid-stride)
#define PRUNE_T 24.0f       // exp2-domain skip threshold
#define GST 104             // LDS row stride for 96-wide bf16 rows

// feature pre-scale folds 1/2 and log2(e): k = exp2(-sum(diff^2))
#define KSA2 (0.84932184f / 160.0f)   // bilateral spatial
#define KSB2 (0.84932184f / 3.0f)     // bilateral color
#define GL2  (1.44269504f / 18.0f)    // spatial kernel exp(-d^2/18) in exp2 units

typedef __attribute__((ext_vector_type(4))) float f32x4;
typedef __attribute__((ext_vector_type(8))) short short8;
typedef __attribute__((ext_vector_type(4))) int int4v;

static __device__ inline unsigned pk_bf16(float a, float b) {
    unsigned ua = __builtin_bit_cast(unsigned, a);
    unsigned ub = __builtin_bit_cast(unsigned, b);
    ua += 0x7FFF + ((ua >> 16) & 1);
    ub += 0x7FFF + ((ub >> 16) & 1);
    return (ua >> 16) | (ub & 0xFFFF0000u);
}
static __device__ inline unsigned short bf16_1(float a) {
    unsigned ua = __builtin_bit_cast(unsigned, a);
    ua += 0x7FFF + ((ua >> 16) & 1);
    return (unsigned short)(ua >> 16);
}

// ---------------- P0: tables + constant smht rows + zero {hist,wlc} --------
__global__ __launch_bounds__(256) void prep_kernel(
    float* __restrict__ sxt, unsigned short* __restrict__ gbt,
    unsigned short* __restrict__ smht, int* __restrict__ gh, int* __restrict__ wlc)
{
    int idx = blockIdx.x * 256 + threadIdx.x;
    if (idx == 0) wlc[0] = 0;
    if (idx < BB * 11 * NN) {
        int b = idx / (11 * NN);
        int rem = idx - b * 11 * NN;
        int r = rem / NN, col = rem - r * NN;
        smht[(size_t)(b * 32 + 21 + r) * NN + col] = (r == 0) ? 0x3F80 : 0;
    }
    if (idx < BB * 4096) gh[idx] = 0;
    if (blockIdx.x == 0) {
        __shared__ float gt[96];
        int t = threadIdx.x;
        if (t < 96) gt[t] = __builtin_amdgcn_exp2f(-(float)(t * t) * GL2);
        __syncthreads();
        if (t < 96) {
            float s = 0.f;
            for (int v = 0; v < 96; v++) s += gt[abs(t - v)];
            sxt[t] = s;
            for (int v = 0; v < 96; v++) gbt[t * 96 + v] = bf16_1(gt[abs(t - v)]);
        }
    }
}

// ---------------- P1: parallel counting sort by 12-bit color cell ----------
__global__ __launch_bounds__(256) void hist_kernel(
    const float* __restrict__ rgb, int* __restrict__ gh)
{
    int idx = blockIdx.x * 256 + threadIdx.x;
    if (idx >= BB * NN) return;
    int b = idx / NN;
    const float* rp = rgb + (size_t)idx * 3;
    int cr = min(15, (int)rp[0] >> 4);
    int cg = min(15, (int)rp[1] >> 4);
    int cb = min(15, (int)rp[2] >> 4);
    atomicAdd(&gh[b * 4096 + ((cr << 8) | (cg << 4) | cb)], 1);
}

__global__ __launch_bounds__(256) void scan_kernel(
    const int* __restrict__ gh, int* __restrict__ goff)
{
    __shared__ int ps[256];
    int t = threadIdx.x, b = blockIdx.x;
    int base = b * 4096 + t * 16;
    int loc[16], s = 0;
#pragma unroll
    for (int k = 0; k < 16; k++) { loc[k] = gh[base + k]; s += loc[k]; }
    ps[t] = s;
    __syncthreads();
    for (int off = 1; off < 256; off <<= 1) {
        int add = (t >= off) ? ps[t - off] : 0;
        __syncthreads();
        ps[t] += add;
        __syncthreads();
    }
    int run = ps[t] - s;
#pragma unroll
    for (int k = 0; k < 16; k++) { goff[base + k] = run; run += loc[k]; }
}

__global__ __launch_bounds__(256) void scatter_kernel(
    const float* __restrict__ rgb, int* __restrict__ goff,
    int* __restrict__ spos, float* __restrict__ fjs)
{
    int idx = blockIdx.x * 256 + threadIdx.x;
    if (idx >= BB * NN) return;
    int b = idx / NN, p = idx - b * NN;
    const float* rp = rgb + (size_t)idx * 3;
    float r = rp[0], g = rp[1], bl = rp[2];
    int cr = min(15, (int)r >> 4);
    int cg = min(15, (int)g >> 4);
    int cb = min(15, (int)bl >> 4);
    int pos = atomicAdd(&goff[b * 4096 + ((cr << 8) | (cg << 4) | cb)], 1);
    spos[idx] = pos;
    int y = p / WW, x = p - y * WW;
    float* fb = fjs + (size_t)b * 5 * NN;
    fb[0 * NN + pos] = r * KSB2;
    fb[1 * NN + pos] = g * KSB2;
    fb[2 * NN + pos] = bl * KSB2;
    fb[3 * NN + pos] = (float)y * KSA2;
    fb[4 * NN + pos] = (float)x * KSA2;
}

// ---------------- P2a: color bbox per sorted 16-tile -----------------------
__global__ __launch_bounds__(256) void bounds_kernel(
    const float* __restrict__ fjs, float* __restrict__ bnd)
{
    int idx = blockIdx.x * 256 + threadIdx.x;
    if (idx >= BB * NT16) return;
    int b = idx / NT16, tile = idx - b * NT16;
    const float* fb = fjs + (size_t)b * 5 * NN + tile * 16;
    float lo[3], hi[3];
#pragma unroll
    for (int f = 0; f < 3; f++) { lo[f] = 1e30f; hi[f] = -1e30f; }
    for (int k = 0; k < 16; k++) {
#pragma unroll
        for (int f = 0; f < 3; f++) {
            float v = fb[f * NN + k];
            lo[f] = fminf(lo[f], v); hi[f] = fmaxf(hi[f], v);
        }
    }
    float* o = bnd + (size_t)idx * 6;
#pragma unroll
    for (int f = 0; f < 3; f++) { o[2 * f] = lo[f]; o[2 * f + 1] = hi[f]; }
}

// ------ P2b: wave-parallel mask + ballot-compact jlist + emit worklist -----
__global__ __launch_bounds__(256) void maskchunks_kernel(
    const float* __restrict__ bnd, unsigned short* __restrict__ jlist,
    int* __restrict__ cnt, int* __restrict__ wl, int* __restrict__ wlc)
{
    int lane = threadIdx.x & 63;
    int bt = blockIdx.x * 4 + (threadIdx.x >> 6);
    if (bt >= BB * NT16) return;
    int b = bt / NT16;
    const float* tb = bnd + (size_t)bt * 6;
    float tlo0 = tb[0], thi0 = tb[1], tlo1 = tb[2], thi1 = tb[3], tlo2 = tb[4], thi2 = tb[5];
    unsigned short* jl = jlist + (size_t)bt * NJB;
    const float* bb = bnd + (size_t)b * NT16 * 6;
    int n = 0;
#pragma unroll
    for (int r = 0; r < 5; r++) {
        int jb = r * 64 + lane;
        bool keep = false;
        if (jb < NJB) {
            const float* a0 = bb + (size_t)(2 * jb) * 6;
            float s = 0.f;
#pragma unroll
            for (int f = 0; f < 3; f++) {
                float jlo = fminf(a0[2 * f], a0[6 + 2 * f]);
                float jhi = fmaxf(a0[2 * f + 1], a0[6 + 2 * f + 1]);
                float lo = (f == 0) ? tlo0 : (f == 1) ? tlo1 : tlo2;
                float hi = (f == 0) ? thi0 : (f == 1) ? thi1 : thi2;
                float gap = fmaxf(0.f, fmaxf(lo - jhi, jlo - hi));
                s = fmaf(gap, gap, s);
            }
            keep = (s <= PRUNE_T);
        }
        unsigned long long m = __ballot(keep);
        if (keep) {
            int pre = __popcll(m & ((1ull << lane) - 1ull));
            jl[n + pre] = (unsigned short)jb;
        }
        n += __popcll(m);
    }
    if (lane == 0) {
        cnt[bt] = n;
        int nsl = (n + CHK - 1) / CHK;
        if (nsl > 0) {
            int base = atomicAdd(wlc, nsl);
            for (int s2 = 0; s2 < nsl; s2++) wl[base + s2] = bt * 64 + s2;
        }
    }
}

// ---------------- K1: per-pixel softmax (iteration 0) ----------------------
__global__ __launch_bounds__(256) void softmax_kernel(
    const float* __restrict__ q, const int* __restrict__ spos,
    unsigned short* __restrict__ smpb, unsigned short* __restrict__ smht,
    float* __restrict__ part)
{
    int idx = blockIdx.x * 256 + threadIdx.x;
    if (idx >= BB * NN) return;
    int b = idx / NN, p = idx - b * NN;
    const float* qp = q + (size_t)idx * CC;
    float v[CC], m = -1e30f;
#pragma unroll
    for (int c = 0; c < CC; c++) { v[c] = qp[c]; m = fmaxf(m, v[c]); }
    float ssum = 0.f;
#pragma unroll
    for (int c = 0; c < CC; c++) { v[c] = __expf(v[c] - m); ssum += v[c]; }
    float inv = 1.0f / ssum;
    int s = spos[idx];
#pragma unroll
    for (int c = 0; c < CC; c++) {
        unsigned short h = bf16_1(v[c] * inv);
        smpb[(size_t)(b * CC + c) * NN + p] = h;
        smht[(size_t)(b * 32 + c) * NN + s] = h;
    }
    float* pp = part + (size_t)(b * NN + s) * 24;
#pragma unroll
    for (int k = 0; k < 24; k++) pp[k] = 0.f;
}

// ---------------- bilateral helpers (depth-2 pipelined j-set) --------------
struct JSet { float vf[5][8]; short8 sb0, sb1; };

static __device__ __forceinline__ void load_jset(
    JSet& s, const float* __restrict__ fb, const unsigned short* __restrict__ smb,
    int jb, int quad, int l16)
{
    int coff = jb * 32 + quad * 8;
#pragma unroll
    for (int f = 0; f < 5; f++) {
        const float4* pf = (const float4*)(fb + (size_t)f * NN + coff);
        float4 lo = pf[0], hi = pf[1];
        s.vf[f][0] = lo.x; s.vf[f][1] = lo.y; s.vf[f][2] = lo.z; s.vf[f][3] = lo.w;
        s.vf[f][4] = hi.x; s.vf[f][5] = hi.y; s.vf[f][6] = hi.z; s.vf[f][7] = hi.w;
    }
    s.sb0 = *(const short8*)(smb + (size_t)l16 * NN + coff);
    s.sb1 = *(const short8*)(smb + (size_t)(16 + l16) * NN + coff);
}

static __device__ __forceinline__ void compute_jset(
    const JSet& s, float fi0, float fi1, float fi2, float fi3, float fi4,
    f32x4& acc0, f32x4& acc1)
{
    float kf[8];
#pragma unroll
    for (int e = 0; e < 8; e++) {
        float d0 = s.vf[0][e] - fi0;
        float d1 = s.vf[1][e] - fi1;
        float d2 = s.vf[2][e] - fi2;
        float d3 = s.vf[3][e] - fi3;
        float d4 = s.vf[4][e] - fi4;
        float sm = d0 * d0;
        sm = fmaf(d1, d1, sm);
        sm = fmaf(d2, d2, sm);
        sm = fmaf(d3, d3, sm);
        sm = fmaf(d4, d4, sm);
        kf[e] = __builtin_amdgcn_exp2f(-sm);
    }
    int4v ap = { (int)pk_bf16(kf[0], kf[1]), (int)pk_bf16(kf[2], kf[3]),
                 (int)pk_bf16(kf[4], kf[5]), (int)pk_bf16(kf[6], kf[7]) };
    short8 afrag = __builtin_bit_cast(short8, ap);
    acc0 = __builtin_amdgcn_mfma_f32_16x16x32_bf16(afrag, s.sb0, acc0, 0, 0, 0);
    acc1 = __builtin_amdgcn_mfma_f32_16x16x32_bf16(afrag, s.sb1, acc1, 0, 0, 0);
}

// ===== K2: conv + bilateral, fused as INDEPENDENT block roles (no sync) ====
// blocks [0,42): conv planes | [42,690): bilateral dense-worklist grid-stride.
__global__ __launch_bounds__(256) void conv_bil_kernel(
    const unsigned short* __restrict__ smpb, const unsigned short* __restrict__ gbt,
    const float* __restrict__ sxt, float* __restrict__ spf,
    const unsigned short* __restrict__ smht_c, const float* __restrict__ fjs,
    const unsigned short* __restrict__ jlist, const int* __restrict__ cntv,
    const int* __restrict__ wl, const int* __restrict__ wlc,
    float* __restrict__ part)
{
    __shared__ unsigned short C1t[96 * GST];   // conv role only (20 KB)
    int tid = threadIdx.x;
    int lane = tid & 63, w = tid >> 6;
    int quad = lane >> 4, l16 = lane & 15;
    int bid = blockIdx.x;

    if (bid < NCONV) {
        // ================= conv role: SP = G @ P @ G =================
        const unsigned short* plane = smpb + (size_t)bid * NN;
        for (int mt = w; mt < 6; mt += 4) {
            int m0 = mt * 16;
            short8 a[3];
#pragma unroll
            for (int kk = 0; kk < 3; kk++)
                a[kk] = *(const short8*)(plane + (size_t)(m0 + l16) * 96 + kk * 32 + quad * 8);
            f32x4 acc[6];
#pragma unroll
            for (int nt = 0; nt < 6; nt++) acc[nt] = (f32x4){0.f, 0.f, 0.f, 0.f};
#pragma unroll
            for (int nt = 0; nt < 6; nt++) {
#pragma unroll
                for (int kk = 0; kk < 3; kk++) {
                    short8 bf = *(const short8*)(gbt + (nt * 16 + l16) * 96 + kk * 32 + quad * 8);
                    acc[nt] = __builtin_amdgcn_mfma_f32_16x16x32_bf16(a[kk], bf, acc[nt], 0, 0, 0);
                }
            }
#pragma unroll
            for (int nt = 0; nt < 6; nt++) {
                unsigned* dst = (unsigned*)&C1t[(nt * 16 + l16) * GST + m0 + quad * 4];
                dst[0] = pk_bf16(acc[nt][0], acc[nt][1]);
                dst[1] = pk_bf16(acc[nt][2], acc[nt][3]);
            }
        }
        __syncthreads();
        float* outp = spf + (size_t)bid * NN;
        for (int mt = w; mt < 6; mt += 4) {
            int m0 = mt * 16;
            short8 a[3];
#pragma unroll
            for (int kk = 0; kk < 3; kk++)
                a[kk] = *(const short8*)(gbt + (m0 + l16) * 96 + kk * 32 + quad * 8);
            f32x4 acc[6];
#pragma unroll
            for (int nt = 0; nt < 6; nt++) acc[nt] = (f32x4){0.f, 0.f, 0.f, 0.f};
#pragma unroll
            for (int nt = 0; nt < 6; nt++) {
#pragma unroll
                for (int kk = 0; kk < 3; kk++) {
                    short8 bf = *(const short8*)&C1t[(nt * 16 + l16) * GST + kk * 32 + quad * 8];
                    acc[nt] = __builtin_amdgcn_mfma_f32_16x16x32_bf16(a[kk], bf, acc[nt], 0, 0, 0);
                }
            }
#pragma unroll
            for (int nt = 0; nt < 6; nt++) {
                int x = nt * 16 + l16;
                float sx = sxt[x];
#pragma unroll
                for (int r = 0; r < 4; r++) {
                    int y = m0 + quad * 4 + r;
                    float invn = __builtin_amdgcn_rcpf(sxt[y] * sx);
                    outp[y * 96 + x] = acc[nt][r] * invn;
                }
            }
        }
        return;
    }

    // ================= bilateral role: dense worklist grid-stride =================
    int nwl = wlc[0];
    for (int widx = (bid - NCONV) * 4 + w; widx < nwl; widx += NBIL * 4) {
        int e = wl[widx];
        int bt = e >> 6, ck = e & 63;
        int cnt = min(cntv[bt] - ck * CHK, CHK);
        int b = bt / NT16, tile16 = bt - b * NT16;
        int i = tile16 * 16 + l16;
        const float* fb = fjs + (size_t)b * 5 * NN;
        float fi0 = fb[0 * NN + i], fi1 = fb[1 * NN + i], fi2 = fb[2 * NN + i];
        float fi3 = fb[3 * NN + i], fi4 = fb[4 * NN + i];
        f32x4 acc0 = {0.f, 0.f, 0.f, 0.f};
        f32x4 acc1 = {0.f, 0.f, 0.f, 0.f};
        const unsigned short* smb = smht_c + (size_t)b * 32 * NN;
        const unsigned short* jl = jlist + (size_t)bt * NJB + ck * CHK;
        JSet A, B;
        load_jset(A, fb, smb, jl[0], quad, l16);
        int k = 0;
        while (true) {
            if (k + 1 < cnt) load_jset(B, fb, smb, jl[k + 1], quad, l16);
            compute_jset(A, fi0, fi1, fi2, fi3, fi4, acc0, acc1);
            if (++k >= cnt) break;
            if (k + 1 < cnt) load_jset(A, fb, smb, jl[k + 1], quad, l16);
            compute_jset(B, fi0, fi1, fi2, fi3, fi4, acc0, acc1);
            if (++k >= cnt) break;
        }
        int ibase = tile16 * 16 + quad * 4;
        float* pr = part + (size_t)b * NN * 24;
#pragma unroll
        for (int r = 0; r < 4; r++)
            atomicAdd(&pr[(size_t)(ibase + r) * 24 + l16], acc0[r]);
        if (l16 < 6) {
#pragma unroll
            for (int r = 0; r < 4; r++)
                atomicAdd(&pr[(size_t)(ibase + r) * 24 + 16 + l16], acc1[r]);
        }
    }
}

// ------- K3: norm + messages + update, fused with next iter's softmax ------
// qout written only on the final iteration (intermediate q lives in SMPB/SMHT)
__global__ __launch_bounds__(256) void update_fused_kernel(
    const float* __restrict__ u, const float* __restrict__ spf,
    float* __restrict__ part, const int* __restrict__ spos,
    const float* __restrict__ Ws, const float* __restrict__ Wb,
    const float* __restrict__ M, float* __restrict__ qout,
    unsigned short* __restrict__ smpb, unsigned short* __restrict__ smht, int wr)
{
    __shared__ float sWs[441], sWb[441], sM[441];
    for (int t = threadIdx.x; t < 441; t += 256) {
        sWs[t] = Ws[t]; sWb[t] = Wb[t]; sM[t] = M[t];
    }
    __syncthreads();
    int idx = blockIdx.x * 256 + threadIdx.x;
    if (idx >= BB * NN) return;
    int b = idx / NN, p = idx - b * NN;
    int s = spos[idx];
    float* pp = part + (size_t)(b * NN + s) * 24;
    float blv[22];
#pragma unroll
    for (int c = 0; c < 22; c++) blv[c] = pp[c];
    float ninv = 1.0f / blv[21];
    float spv[CC], msg[CC];
#pragma unroll
    for (int c = 0; c < CC; c++) {
        blv[c] *= ninv;
        spv[c] = spf[(size_t)(b * CC + c) * NN + p];
    }
#pragma unroll
    for (int c = 0; c < CC; c++) {
        float a = 0.f;
        const float* wr2 = &sWs[c * CC];
        const float* br = &sWb[c * CC];
#pragma unroll
        for (int c2 = 0; c2 < CC; c2++) a = fmaf(wr2[c2], spv[c2], a);
#pragma unroll
        for (int c2 = 0; c2 < CC; c2++) a = fmaf(br[c2], blv[c2], a);
        msg[c] = a;
    }
    const float* up = u + (size_t)idx * CC;
    float qv[CC];
#pragma unroll
    for (int c = 0; c < CC; c++) {
        float a = up[c];
        const float* mr = &sM[c * CC];
#pragma unroll
        for (int c2 = 0; c2 < CC; c2++) a = fmaf(-mr[c2], msg[c2], a);
        qv[c] = a;
    }
    if (wr) {
        // fused softmax of the new q for the next iteration
        float m = -1e30f;
#pragma unroll
        for (int c = 0; c < CC; c++) m = fmaxf(m, qv[c]);
        float ssum = 0.f;
        float ev[CC];
#pragma unroll
        for (int c = 0; c < CC; c++) { ev[c] = __expf(qv[c] - m); ssum += ev[c]; }
        float inv = 1.0f / ssum;
#pragma unroll
        for (int c = 0; c < CC; c++) {
            unsigned short h = bf16_1(ev[c] * inv);
            smpb[(size_t)(b * CC + c) * NN + p] = h;
            smht[(size_t)(b * 32 + c) * NN + s] = h;
        }
#pragma unroll
        for (int k = 0; k < 24; k++) pp[k] = 0.f;   // zero PART for next iter
    } else {
        float* qp = qout + (size_t)idx * CC;
#pragma unroll
        for (int c = 0; c < CC; c++) qp[c] = qv[c];
    }
}

extern "C" void kernel_launch(void* const* d_in, const int* in_sizes, int n_in,
                              void* d_out, int out_size, void* d_ws, size_t ws_size,
                              hipStream_t stream)
{
    const float* unary = (const float*)d_in[0];  // [B,H,W,C]
    const float* rgb   = (const float*)d_in[1];  // [B,H,W,3]
    const float* Ws    = (const float*)d_in[2];
    const float* Wb    = (const float*)d_in[3];
    const float* M     = (const float*)d_in[4];
    float* out = (float*)d_out;                  // [B,N,C]

    float* SXT  = (float*)d_ws;                            // 96
    float* FJS  = SXT + 96;                                // B*5*N
    float* SPF  = FJS + (size_t)BB * 5 * NN;               // B*21*N
    float* PART = SPF + (size_t)BB * CC * NN;              // B*N*24
    float* BND  = PART + (size_t)BB * NN * 24;             // B*576*6
    int*   SPOS = (int*)(BND + (size_t)BB * NT16 * 6);     // B*N
    int*   GH   = SPOS + BB * NN;                          // B*4096
    int*   GOFF = GH + BB * 4096;                          // B*4096
    int*   CNT  = GOFF + BB * 4096;                        // B*576
    int*   WLC  = CNT + BB * NT16;                         // 1
    int*   WL   = WLC + 1;                                 // <= B*576*36
    unsigned short* JL = (unsigned short*)(WL + BB * NT16 * 36);  // B*576*288
    unsigned short* SMHT = JL + (size_t)BB * NT16 * NJB;   // B*32*N
    unsigned short* SMPB = SMHT + (size_t)BB * 32 * NN;    // B*21*N
    unsigned short* GBT  = SMPB + (size_t)BB * CC * NN;    // 96*96

    prep_kernel<<<(BB * 11 * NN + 255) / 256, 256, 0, stream>>>(SXT, GBT, SMHT, GH, WLC);
    hist_kernel<<<(BB * NN + 255) / 256, 256, 0, stream>>>(rgb, GH);
    scan_kernel<<<BB, 256, 0, stream>>>(GH, GOFF);
    scatter_kernel<<<(BB * NN + 255) / 256, 256, 0, stream>>>(rgb, GOFF, SPOS, FJS);
    bounds_kernel<<<(BB * NT16 + 255) / 256, 256, 0, stream>>>(FJS, BND);
    maskchunks_kernel<<<(BB * NT16 + 3) / 4, 256, 0, stream>>>(BND, JL, CNT, WL, WLC);

    softmax_kernel<<<(BB * NN + 255) / 256, 256, 0, stream>>>(unary, SPOS, SMPB, SMHT, PART);
    for (int it = 0; it < 5; ++it) {
        conv_bil_kernel<<<NCONV + NBIL, 256, 0, stream>>>(
            SMPB, GBT, SXT, SPF, SMHT, FJS, JL, CNT, WL, WLC, PART);
        update_fused_kernel<<<(BB * NN + 255) / 256, 256, 0, stream>>>(
            unary, SPF, PART, SPOS, Ws, Wb, M, out, SMPB, SMHT, (it < 4) ? 1 : 0);
    }
}

// Round 11
// 309.379 us; speedup vs baseline: 2.2951x; 1.0202x over previous
//
#include <hip/hip_runtime.h>

#define HH 96
#define WW 96
#define CC 21
#define BB 2
#define NN (HH*WW)          // 9216
#define NT16 (NN/16)        // 576 sorted 16-tiles per batch
#define NJB  (NN/32)        // 288 j-blocks per batch
#define CHK 8               // kept-jblocks per worklist slot
#define NCONV (BB*CC)       // 42 conv blocks
#define NBIL 648            // bilateral blocks (2592 waves, grid-stride)
#define PRUNE_T 24.0f       // exp2-domain skip threshold
#define GST 104             // LDS row stride for 96-wide bf16 rows

// feature pre-scale folds 1/2 and log2(e): k = exp2(-sum(diff^2))
#define KSA2 (0.84932184f / 160.0f)   // bilateral spatial
#define KSB2 (0.84932184f / 3.0f)     // bilateral color
#define GL2  (1.44269504f / 18.0f)    // spatial kernel exp(-d^2/18) in exp2 units

typedef __attribute__((ext_vector_type(4))) float f32x4;
typedef __attribute__((ext_vector_type(8))) short short8;
typedef __attribute__((ext_vector_type(4))) int int4v;

static __device__ inline unsigned pk_bf16(float a, float b) {
    unsigned ua = __builtin_bit_cast(unsigned, a);
    unsigned ub = __builtin_bit_cast(unsigned, b);
    ua += 0x7FFF + ((ua >> 16) & 1);
    ub += 0x7FFF + ((ub >> 16) & 1);
    return (ua >> 16) | (ub & 0xFFFF0000u);
}
static __device__ inline unsigned short bf16_1(float a) {
    unsigned ua = __builtin_bit_cast(unsigned, a);
    ua += 0x7FFF + ((ua >> 16) & 1);
    return (unsigned short)(ua >> 16);
}

// ===== D1: hist (on poisoned base) + tables + smht const rows + BND-hi zero =
// gh starts at the ws poison value; consumers subtract the sentinel.
__global__ __launch_bounds__(256) void histprep_kernel(
    const float* __restrict__ rgb, unsigned* __restrict__ gh,
    float* __restrict__ sxt, unsigned short* __restrict__ gbt,
    unsigned short* __restrict__ smht, unsigned* __restrict__ bnd)
{
    int tid = threadIdx.x;
    int gid = blockIdx.x * 256 + tid;
    // hist role (blocks 0..71)
    if (gid < BB * NN) {
        int b = gid / NN;
        const float* rp = rgb + (size_t)gid * 3;
        int cr = min(15, (int)rp[0] >> 4);
        int cg = min(15, (int)rp[1] >> 4);
        int cb = min(15, (int)rp[2] >> 4);
        atomicAdd(&gh[b * 4096 + ((cr << 8) | (cg << 4) | cb)], 1u);
    }
    // smht constant rows 21..31 (dword fill)
    unsigned* smd = (unsigned*)smht;
    for (int o = gid; o < BB * 11 * (NN / 2); o += 104 * 256) {
        int b = o / (11 * (NN / 2));
        int rem = o - b * 11 * (NN / 2);
        int rr = rem / (NN / 2), col = rem - rr * (NN / 2);
        smd[(size_t)(b * 32 + 21 + rr) * (NN / 2) + col] = (rr == 0) ? 0x3F803F80u : 0u;
    }
    // BND hi slots -> 0 (atomicMax identity for positive-float bits)
    if (gid < BB * NT16 * 3) {
        int t2 = gid / 3, f = gid - t2 * 3;
        bnd[t2 * 6 + 2 * f + 1] = 0u;
    }
    // tables role (block 0)
    if (blockIdx.x == 0) {
        __shared__ float gt[96];
        if (tid < 96) gt[tid] = __builtin_amdgcn_exp2f(-(float)(tid * tid) * GL2);
        __syncthreads();
        if (tid < 96) {
            float s = 0.f;
            for (int v = 0; v < 96; v++) s += gt[abs(tid - v)];
            sxt[tid] = s;
            for (int v = 0; v < 96; v++) gbt[tid * 96 + v] = bf16_1(gt[abs(tid - v)]);
        }
    }
}

// ===== D2: scan (per batch block), sentinel-relative counts ================
__global__ __launch_bounds__(256) void scan_kernel(
    const unsigned* __restrict__ gh, int* __restrict__ goff,
    const unsigned* __restrict__ sent)
{
    __shared__ int ps[256];
    unsigned sv = sent[0];
    int t = threadIdx.x, b = blockIdx.x;
    int base = b * 4096 + t * 16;
    int loc[16], s = 0;
#pragma unroll
    for (int k = 0; k < 16; k++) { loc[k] = (int)(gh[base + k] - sv); s += loc[k]; }
    ps[t] = s;
    __syncthreads();
    for (int off = 1; off < 256; off <<= 1) {
        int add = (t >= off) ? ps[t - off] : 0;
        __syncthreads();
        ps[t] += add;
        __syncthreads();
    }
    int run = ps[t] - s;
#pragma unroll
    for (int k = 0; k < 16; k++) { goff[base + k] = run; run += loc[k]; }
}

// ===== D3: scatter + per-tile bbox via unsigned float-bit atomics ==========
__global__ __launch_bounds__(256) void scatter_kernel(
    const float* __restrict__ rgb, int* __restrict__ goff,
    int* __restrict__ spos, float* __restrict__ fjs, unsigned* __restrict__ bnd)
{
    int idx = blockIdx.x * 256 + threadIdx.x;
    if (idx >= BB * NN) return;
    int b = idx / NN, p = idx - b * NN;
    const float* rp = rgb + (size_t)idx * 3;
    float r = rp[0], g = rp[1], bl = rp[2];
    int cr = min(15, (int)r >> 4);
    int cg = min(15, (int)g >> 4);
    int cb = min(15, (int)bl >> 4);
    int pos = atomicAdd(&goff[b * 4096 + ((cr << 8) | (cg << 4) | cb)], 1);
    spos[idx] = pos;
    int y = p / WW, x = p - y * WW;
    float fr = r * KSB2, fg = g * KSB2, fb2 = bl * KSB2;
    float* fb = fjs + (size_t)b * 5 * NN;
    fb[0 * NN + pos] = fr;
    fb[1 * NN + pos] = fg;
    fb[2 * NN + pos] = fb2;
    fb[3 * NN + pos] = (float)y * KSA2;
    fb[4 * NN + pos] = (float)x * KSA2;
    unsigned* bq = bnd + (size_t)(b * NT16 + (pos >> 4)) * 6;
    atomicMin(&bq[0], __float_as_uint(fr));  atomicMax(&bq[1], __float_as_uint(fr));
    atomicMin(&bq[2], __float_as_uint(fg));  atomicMax(&bq[3], __float_as_uint(fg));
    atomicMin(&bq[4], __float_as_uint(fb2)); atomicMax(&bq[5], __float_as_uint(fb2));
}

// ===== D4: maskchunks (blocks 0..287) + iteration-0 softmax (288..359) =====
__global__ __launch_bounds__(256) void masksoft_kernel(
    const float* __restrict__ bnd, unsigned short* __restrict__ jlist,
    int* __restrict__ cnt, int* __restrict__ wl, unsigned* __restrict__ wlc,
    const unsigned* __restrict__ sent,
    const float* __restrict__ q, const int* __restrict__ spos,
    unsigned short* __restrict__ smpb, unsigned short* __restrict__ smht,
    float* __restrict__ part)
{
    int tid = threadIdx.x;
    if (blockIdx.x < 288) {
        int lane = tid & 63;
        int bt = blockIdx.x * 4 + (tid >> 6);
        if (bt >= BB * NT16) return;
        int b = bt / NT16;
        const float* tb = bnd + (size_t)bt * 6;
        float tlo0 = tb[0], thi0 = tb[1], tlo1 = tb[2], thi1 = tb[3], tlo2 = tb[4], thi2 = tb[5];
        unsigned short* jl = jlist + (size_t)bt * NJB;
        const float* bb = bnd + (size_t)b * NT16 * 6;
        int n = 0;
#pragma unroll
        for (int r = 0; r < 5; r++) {
            int jb = r * 64 + lane;
            bool keep = false;
            if (jb < NJB) {
                const float* a0 = bb + (size_t)(2 * jb) * 6;
                float s = 0.f;
#pragma unroll
                for (int f = 0; f < 3; f++) {
                    float jlo = fminf(a0[2 * f], a0[6 + 2 * f]);
                    float jhi = fmaxf(a0[2 * f + 1], a0[6 + 2 * f + 1]);
                    float lo = (f == 0) ? tlo0 : (f == 1) ? tlo1 : tlo2;
                    float hi = (f == 0) ? thi0 : (f == 1) ? thi1 : thi2;
                    float gap = fmaxf(0.f, fmaxf(lo - jhi, jlo - hi));
                    s = fmaf(gap, gap, s);
                }
                keep = (s <= PRUNE_T);
            }
            unsigned long long m = __ballot(keep);
            if (keep) {
                int pre = __popcll(m & ((1ull << lane) - 1ull));
                jl[n + pre] = (unsigned short)jb;
            }
            n += __popcll(m);
        }
        if (lane == 0) {
            cnt[bt] = n;
            int nsl = (n + CHK - 1) / CHK;
            if (nsl > 0) {
                int base = (int)(atomicAdd(wlc, (unsigned)nsl) - sent[0]);
                for (int s2 = 0; s2 < nsl; s2++) wl[base + s2] = bt * 64 + s2;
            }
        }
        return;
    }
    // softmax role
    int idx = (blockIdx.x - 288) * 256 + tid;
    if (idx >= BB * NN) return;
    int b = idx / NN, p = idx - b * NN;
    const float* qp = q + (size_t)idx * CC;
    float v[CC], m = -1e30f;
#pragma unroll
    for (int c = 0; c < CC; c++) { v[c] = qp[c]; m = fmaxf(m, v[c]); }
    float ssum = 0.f;
#pragma unroll
    for (int c = 0; c < CC; c++) { v[c] = __expf(v[c] - m); ssum += v[c]; }
    float inv = 1.0f / ssum;
    int s = spos[idx];
#pragma unroll
    for (int c = 0; c < CC; c++) {
        unsigned short h = bf16_1(v[c] * inv);
        smpb[(size_t)(b * CC + c) * NN + p] = h;
        smht[(size_t)(b * 32 + c) * NN + s] = h;
    }
    float* pp = part + (size_t)(b * NN + s) * 24;
#pragma unroll
    for (int k = 0; k < 24; k++) pp[k] = 0.f;
}

// ---------------- bilateral helpers (depth-2 pipelined j-set) --------------
struct JSet { float vf[5][8]; short8 sb0, sb1; };

static __device__ __forceinline__ void load_jset(
    JSet& s, const float* __restrict__ fb, const unsigned short* __restrict__ smb,
    int jb, int quad, int l16)
{
    int coff = jb * 32 + quad * 8;
#pragma unroll
    for (int f = 0; f < 5; f++) {
        const float4* pf = (const float4*)(fb + (size_t)f * NN + coff);
        float4 lo = pf[0], hi = pf[1];
        s.vf[f][0] = lo.x; s.vf[f][1] = lo.y; s.vf[f][2] = lo.z; s.vf[f][3] = lo.w;
        s.vf[f][4] = hi.x; s.vf[f][5] = hi.y; s.vf[f][6] = hi.z; s.vf[f][7] = hi.w;
    }
    s.sb0 = *(const short8*)(smb + (size_t)l16 * NN + coff);
    s.sb1 = *(const short8*)(smb + (size_t)(16 + l16) * NN + coff);
}

static __device__ __forceinline__ void compute_jset(
    const JSet& s, float fi0, float fi1, float fi2, float fi3, float fi4,
    f32x4& acc0, f32x4& acc1)
{
    float kf[8];
#pragma unroll
    for (int e = 0; e < 8; e++) {
        float d0 = s.vf[0][e] - fi0;
        float d1 = s.vf[1][e] - fi1;
        float d2 = s.vf[2][e] - fi2;
        float d3 = s.vf[3][e] - fi3;
        float d4 = s.vf[4][e] - fi4;
        float sm = d0 * d0;
        sm = fmaf(d1, d1, sm);
        sm = fmaf(d2, d2, sm);
        sm = fmaf(d3, d3, sm);
        sm = fmaf(d4, d4, sm);
        kf[e] = __builtin_amdgcn_exp2f(-sm);
    }
    int4v ap = { (int)pk_bf16(kf[0], kf[1]), (int)pk_bf16(kf[2], kf[3]),
                 (int)pk_bf16(kf[4], kf[5]), (int)pk_bf16(kf[6], kf[7]) };
    short8 afrag = __builtin_bit_cast(short8, ap);
    acc0 = __builtin_amdgcn_mfma_f32_16x16x32_bf16(afrag, s.sb0, acc0, 0, 0, 0);
    acc1 = __builtin_amdgcn_mfma_f32_16x16x32_bf16(afrag, s.sb1, acc1, 0, 0, 0);
}

// ===== K2: conv + bilateral, independent block roles (no sync) =============
__global__ __launch_bounds__(256) void conv_bil_kernel(
    const unsigned short* __restrict__ smpb, const unsigned short* __restrict__ gbt,
    const float* __restrict__ sxt, float* __restrict__ spf,
    const unsigned short* __restrict__ smht_c, const float* __restrict__ fjs,
    const unsigned short* __restrict__ jlist, const int* __restrict__ cntv,
    const int* __restrict__ wl, const unsigned* __restrict__ wlc,
    const unsigned* __restrict__ sent, float* __restrict__ part)
{
    __shared__ unsigned short C1t[96 * GST];   // conv role only (20 KB)
    int tid = threadIdx.x;
    int lane = tid & 63, w = tid >> 6;
    int quad = lane >> 4, l16 = lane & 15;
    int bid = blockIdx.x;

    if (bid < NCONV) {
        const unsigned short* plane = smpb + (size_t)bid * NN;
        for (int mt = w; mt < 6; mt += 4) {
            int m0 = mt * 16;
            short8 a[3];
#pragma unroll
            for (int kk = 0; kk < 3; kk++)
                a[kk] = *(const short8*)(plane + (size_t)(m0 + l16) * 96 + kk * 32 + quad * 8);
            f32x4 acc[6];
#pragma unroll
            for (int nt = 0; nt < 6; nt++) acc[nt] = (f32x4){0.f, 0.f, 0.f, 0.f};
#pragma unroll
            for (int nt = 0; nt < 6; nt++) {
#pragma unroll
                for (int kk = 0; kk < 3; kk++) {
                    short8 bf = *(const short8*)(gbt + (nt * 16 + l16) * 96 + kk * 32 + quad * 8);
                    acc[nt] = __builtin_amdgcn_mfma_f32_16x16x32_bf16(a[kk], bf, acc[nt], 0, 0, 0);
                }
            }
#pragma unroll
            for (int nt = 0; nt < 6; nt++) {
                unsigned* dst = (unsigned*)&C1t[(nt * 16 + l16) * GST + m0 + quad * 4];
                dst[0] = pk_bf16(acc[nt][0], acc[nt][1]);
                dst[1] = pk_bf16(acc[nt][2], acc[nt][3]);
            }
        }
        __syncthreads();
        float* outp = spf + (size_t)bid * NN;
        for (int mt = w; mt < 6; mt += 4) {
            int m0 = mt * 16;
            short8 a[3];
#pragma unroll
            for (int kk = 0; kk < 3; kk++)
                a[kk] = *(const short8*)(gbt + (m0 + l16) * 96 + kk * 32 + quad * 8);
            f32x4 acc[6];
#pragma unroll
            for (int nt = 0; nt < 6; nt++) acc[nt] = (f32x4){0.f, 0.f, 0.f, 0.f};
#pragma unroll
            for (int nt = 0; nt < 6; nt++) {
#pragma unroll
                for (int kk = 0; kk < 3; kk++) {
                    short8 bf = *(const short8*)&C1t[(nt * 16 + l16) * GST + kk * 32 + quad * 8];
                    acc[nt] = __builtin_amdgcn_mfma_f32_16x16x32_bf16(a[kk], bf, acc[nt], 0, 0, 0);
                }
            }
#pragma unroll
            for (int nt = 0; nt < 6; nt++) {
                int x = nt * 16 + l16;
                float sx = sxt[x];
#pragma unroll
                for (int r = 0; r < 4; r++) {
                    int y = m0 + quad * 4 + r;
                    float invn = __builtin_amdgcn_rcpf(sxt[y] * sx);
                    outp[y * 96 + x] = acc[nt][r] * invn;
                }
            }
        }
        return;
    }

    int nwl = (int)(wlc[0] - sent[0]);
    for (int widx = (bid - NCONV) * 4 + w; widx < nwl; widx += NBIL * 4) {
        int e = wl[widx];
        int bt = e >> 6, ck = e & 63;
        int cnt = min(cntv[bt] - ck * CHK, CHK);
        int b = bt / NT16, tile16 = bt - b * NT16;
        int i = tile16 * 16 + l16;
        const float* fb = fjs + (size_t)b * 5 * NN;
        float fi0 = fb[0 * NN + i], fi1 = fb[1 * NN + i], fi2 = fb[2 * NN + i];
        float fi3 = fb[3 * NN + i], fi4 = fb[4 * NN + i];
        f32x4 acc0 = {0.f, 0.f, 0.f, 0.f};
        f32x4 acc1 = {0.f, 0.f, 0.f, 0.f};
        const unsigned short* smb = smht_c + (size_t)b * 32 * NN;
        const unsigned short* jl = jlist + (size_t)bt * NJB + ck * CHK;
        JSet A, B;
        load_jset(A, fb, smb, jl[0], quad, l16);
        int k = 0;
        while (true) {
            if (k + 1 < cnt) load_jset(B, fb, smb, jl[k + 1], quad, l16);
            compute_jset(A, fi0, fi1, fi2, fi3, fi4, acc0, acc1);
            if (++k >= cnt) break;
            if (k + 1 < cnt) load_jset(A, fb, smb, jl[k + 1], quad, l16);
            compute_jset(B, fi0, fi1, fi2, fi3, fi4, acc0, acc1);
            if (++k >= cnt) break;
        }
        int ibase = tile16 * 16 + quad * 4;
        float* pr = part + (size_t)b * NN * 24;
#pragma unroll
        for (int r = 0; r < 4; r++)
            atomicAdd(&pr[(size_t)(ibase + r) * 24 + l16], acc0[r]);
        if (l16 < 6) {
#pragma unroll
            for (int r = 0; r < 4; r++)
                atomicAdd(&pr[(size_t)(ibase + r) * 24 + 16 + l16], acc1[r]);
        }
    }
}

// ------- K3: norm + messages + update + next-iter softmax (144x128) --------
__global__ __launch_bounds__(128) void update_fused_kernel(
    const float* __restrict__ u, const float* __restrict__ spf,
    float* __restrict__ part, const int* __restrict__ spos,
    const float* __restrict__ Ws, const float* __restrict__ Wb,
    const float* __restrict__ M, float* __restrict__ qout,
    unsigned short* __restrict__ smpb, unsigned short* __restrict__ smht, int wr)
{
    __shared__ float sWs[441], sWb[441], sM[441];
    for (int t = threadIdx.x; t < 441; t += 128) {
        sWs[t] = Ws[t]; sWb[t] = Wb[t]; sM[t] = M[t];
    }
    __syncthreads();
    int idx = blockIdx.x * 128 + threadIdx.x;
    if (idx >= BB * NN) return;
    int b = idx / NN, p = idx - b * NN;
    int s = spos[idx];
    float* pp = part + (size_t)(b * NN + s) * 24;
    float blv[22];
#pragma unroll
    for (int c = 0; c < 22; c++) blv[c] = pp[c];
    float ninv = 1.0f / blv[21];
    float spv[CC], msg[CC];
#pragma unroll
    for (int c = 0; c < CC; c++) {
        blv[c] *= ninv;
        spv[c] = spf[(size_t)(b * CC + c) * NN + p];
    }
#pragma unroll
    for (int c = 0; c < CC; c++) {
        float a = 0.f;
        const float* wr2 = &sWs[c * CC];
        const float* br = &sWb[c * CC];
#pragma unroll
        for (int c2 = 0; c2 < CC; c2++) a = fmaf(wr2[c2], spv[c2], a);
#pragma unroll
        for (int c2 = 0; c2 < CC; c2++) a = fmaf(br[c2], blv[c2], a);
        msg[c] = a;
    }
    const float* up = u + (size_t)idx * CC;
    float qv[CC];
#pragma unroll
    for (int c = 0; c < CC; c++) {
        float a = up[c];
        const float* mr = &sM[c * CC];
#pragma unroll
        for (int c2 = 0; c2 < CC; c2++) a = fmaf(-mr[c2], msg[c2], a);
        qv[c] = a;
    }
    if (wr) {
        float m = -1e30f;
#pragma unroll
        for (int c = 0; c < CC; c++) m = fmaxf(m, qv[c]);
        float ssum = 0.f;
        float ev[CC];
#pragma unroll
        for (int c = 0; c < CC; c++) { ev[c] = __expf(qv[c] - m); ssum += ev[c]; }
        float inv = 1.0f / ssum;
#pragma unroll
        for (int c = 0; c < CC; c++) {
            unsigned short h = bf16_1(ev[c] * inv);
            smpb[(size_t)(b * CC + c) * NN + p] = h;
            smht[(size_t)(b * 32 + c) * NN + s] = h;
        }
#pragma unroll
        for (int k = 0; k < 24; k++) pp[k] = 0.f;
    } else {
        float* qp = qout + (size_t)idx * CC;
#pragma unroll
        for (int c = 0; c < CC; c++) qp[c] = qv[c];
    }
}

extern "C" void kernel_launch(void* const* d_in, const int* in_sizes, int n_in,
                              void* d_out, int out_size, void* d_ws, size_t ws_size,
                              hipStream_t stream)
{
    const float* unary = (const float*)d_in[0];  // [B,H,W,C]
    const float* rgb   = (const float*)d_in[1];  // [B,H,W,3]
    const float* Ws    = (const float*)d_in[2];
    const float* Wb    = (const float*)d_in[3];
    const float* M     = (const float*)d_in[4];
    float* out = (float*)d_out;                  // [B,N,C]

    float* SXT  = (float*)d_ws;                            // 96
    float* FJS  = SXT + 96;                                // B*5*N
    float* SPF  = FJS + (size_t)BB * 5 * NN;               // B*21*N
    float* PART = SPF + (size_t)BB * CC * NN;              // B*N*24
    unsigned* BND = (unsigned*)(PART + (size_t)BB * NN * 24);  // B*576*6
    int*   SPOS = (int*)(BND + (size_t)BB * NT16 * 6);     // B*N
    unsigned* GH = (unsigned*)(SPOS + BB * NN);            // B*4096 (poison-based)
    int*   GOFF = (int*)(GH + BB * 4096);                  // B*4096
    int*   CNT  = GOFF + BB * 4096;                        // B*576
    unsigned* WLC = (unsigned*)(CNT + BB * NT16);          // 1 (poison-based)
    unsigned* SENT = WLC + 1;                              // 1 (NEVER written)
    int*   WL   = (int*)(SENT + 1);                        // <= B*576*36
    unsigned short* JL = (unsigned short*)(WL + BB * NT16 * 36);  // B*576*288
    unsigned short* SMHT = JL + (size_t)BB * NT16 * NJB;   // B*32*N
    unsigned short* SMPB = SMHT + (size_t)BB * 32 * NN;    // B*21*N
    unsigned short* GBT  = SMPB + (size_t)BB * CC * NN;    // 96*96

    histprep_kernel<<<104, 256, 0, stream>>>(rgb, GH, SXT, GBT, SMHT, BND);
    scan_kernel<<<BB, 256, 0, stream>>>(GH, GOFF, SENT);
    scatter_kernel<<<(BB * NN + 255) / 256, 256, 0, stream>>>(rgb, GOFF, SPOS, FJS, BND);
    masksoft_kernel<<<360, 256, 0, stream>>>((const float*)BND, JL, CNT, WL, WLC, SENT,
                                             unary, SPOS, SMPB, SMHT, PART);
    for (int it = 0; it < 5; ++it) {
        conv_bil_kernel<<<NCONV + NBIL, 256, 0, stream>>>(
            SMPB, GBT, SXT, SPF, SMHT, FJS, JL, CNT, WL, WLC, SENT, PART);
        update_fused_kernel<<<(BB * NN + 127) / 128, 128, 0, stream>>>(
            unary, SPF, PART, SPOS, Ws, Wb, M, out, SMPB, SMHT, (it < 4) ? 1 : 0);
    }
}

// Round 12
// 296.863 us; speedup vs baseline: 2.3918x; 1.0422x over previous
//
#include <hip/hip_runtime.h>

#define HH 96
#define WW 96
#define CC 21
#define BB 2
#define NN (HH*WW)          // 9216
#define NT16 (NN/16)        // 576 sorted 16-tiles per batch
#define NJB  (NN/32)        // 288 j-blocks per batch
#define CHK 8               // kept-jblocks per worklist slot
#define NCONV (BB*CC)       // 42 conv blocks
#define NBIL 648            // bilateral blocks (2592 waves, grid-stride)
#define PRUNE_T 20.0f       // exp2-domain skip threshold (mass <= N*2^-20)
#define GST 104             // LDS row stride for 96-wide bf16 rows

// feature pre-scale folds 1/2 and log2(e): k = exp2(-sum(diff^2))
#define KSA2 (0.84932184f / 160.0f)   // bilateral spatial
#define KSB2 (0.84932184f / 3.0f)     // bilateral color
#define GL2  (1.44269504f / 18.0f)    // spatial kernel exp(-d^2/18) in exp2 units

typedef __attribute__((ext_vector_type(4))) float f32x4;
typedef __attribute__((ext_vector_type(8))) short short8;
typedef __attribute__((ext_vector_type(4))) int int4v;

static __device__ inline unsigned pk_bf16(float a, float b) {
    unsigned ua = __builtin_bit_cast(unsigned, a);
    unsigned ub = __builtin_bit_cast(unsigned, b);
    ua += 0x7FFF + ((ua >> 16) & 1);
    ub += 0x7FFF + ((ub >> 16) & 1);
    return (ua >> 16) | (ub & 0xFFFF0000u);
}
static __device__ inline unsigned short bf16_1(float a) {
    unsigned ua = __builtin_bit_cast(unsigned, a);
    ua += 0x7FFF + ((ua >> 16) & 1);
    return (unsigned short)(ua >> 16);
}

// ===== D1: dual hist (poison-based) + tables + smht const rows + BND-hi 0 ==
__global__ __launch_bounds__(256) void histprep_kernel(
    const float* __restrict__ rgb, unsigned* __restrict__ gha,
    unsigned* __restrict__ ghb, float* __restrict__ sxt,
    unsigned short* __restrict__ gbt, unsigned short* __restrict__ smht,
    unsigned* __restrict__ bnd)
{
    int tid = threadIdx.x;
    int gid = blockIdx.x * 256 + tid;
    if (gid < BB * NN) {
        int b = gid / NN;
        const float* rp = rgb + (size_t)gid * 3;
        int cr = min(15, (int)rp[0] >> 4);
        int cg = min(15, (int)rp[1] >> 4);
        int cb = min(15, (int)rp[2] >> 4);
        int cell = b * 4096 + ((cr << 8) | (cg << 4) | cb);
        atomicAdd(&gha[cell], 1u);
        atomicAdd(&ghb[cell], 1u);
    }
    unsigned* smd = (unsigned*)smht;
    for (int o = gid; o < BB * 11 * (NN / 2); o += 104 * 256) {
        int b = o / (11 * (NN / 2));
        int rem = o - b * 11 * (NN / 2);
        int rr = rem / (NN / 2), col = rem - rr * (NN / 2);
        smd[(size_t)(b * 32 + 21 + rr) * (NN / 2) + col] = (rr == 0) ? 0x3F803F80u : 0u;
    }
    if (gid < BB * NT16 * 3) {
        int t2 = gid / 3, f = gid - t2 * 3;
        bnd[t2 * 6 + 2 * f + 1] = 0u;
    }
    if (blockIdx.x == 0) {
        __shared__ float gt[96];
        if (tid < 96) gt[tid] = __builtin_amdgcn_exp2f(-(float)(tid * tid) * GL2);
        __syncthreads();
        if (tid < 96) {
            float s = 0.f;
            for (int v = 0; v < 96; v++) s += gt[abs(tid - v)];
            sxt[tid] = s;
            for (int v = 0; v < 96; v++) gbt[tid * 96 + v] = bf16_1(gt[abs(tid - v)]);
        }
    }
}

// ===== D2: fused scan + scatter + bbox =====================================
// Each block redundantly scans its batch's 4096-bin histogram (copy A) in
// LDS, then allocates unique sorted positions via atomicSub on copy B.
__global__ __launch_bounds__(256) void scanscatter_kernel(
    const float* __restrict__ rgb, const unsigned* __restrict__ gha,
    unsigned* __restrict__ ghb, const unsigned* __restrict__ sent,
    int* __restrict__ spos, float* __restrict__ fjs, unsigned* __restrict__ bnd)
{
    __shared__ int sOff[4096];
    __shared__ int ps[256];
    unsigned sv = sent[0];
    int t = threadIdx.x;
    int blk = blockIdx.x;
    int b = blk / (36);                       // 36 blocks per batch
    // phase 1: block-local exclusive scan of this batch's histogram
    int base = b * 4096 + t * 16;
    int loc[16], s = 0;
#pragma unroll
    for (int k = 0; k < 16; k++) { loc[k] = (int)(gha[base + k] - sv); s += loc[k]; }
    ps[t] = s;
    __syncthreads();
    for (int off = 1; off < 256; off <<= 1) {
        int add = (t >= off) ? ps[t - off] : 0;
        __syncthreads();
        ps[t] += add;
        __syncthreads();
    }
    int run = ps[t] - s;
#pragma unroll
    for (int k = 0; k < 16; k++) { sOff[t * 16 + k] = run; run += loc[k]; }
    __syncthreads();
    // phase 2: scatter this block's 256 pixels
    int idx = blk * 256 + t;                  // global pixel, == b*NN + p
    int p = idx - b * NN;
    const float* rp = rgb + (size_t)idx * 3;
    float r = rp[0], g = rp[1], bl = rp[2];
    int cr = min(15, (int)r >> 4);
    int cg = min(15, (int)g >> 4);
    int cb = min(15, (int)bl >> 4);
    int cell = (cr << 8) | (cg << 4) | cb;
    unsigned old = atomicSub(&ghb[b * 4096 + cell], 1u);
    int pos = sOff[cell] + (int)(old - sv) - 1;
    spos[idx] = pos;
    int y = p / WW, x = p - y * WW;
    float fr = r * KSB2, fg = g * KSB2, fb2 = bl * KSB2;
    float* fb = fjs + (size_t)b * 5 * NN;
    fb[0 * NN + pos] = fr;
    fb[1 * NN + pos] = fg;
    fb[2 * NN + pos] = fb2;
    fb[3 * NN + pos] = (float)y * KSA2;
    fb[4 * NN + pos] = (float)x * KSA2;
    unsigned* bq = bnd + (size_t)(b * NT16 + (pos >> 4)) * 6;
    atomicMin(&bq[0], __float_as_uint(fr));  atomicMax(&bq[1], __float_as_uint(fr));
    atomicMin(&bq[2], __float_as_uint(fg));  atomicMax(&bq[3], __float_as_uint(fg));
    atomicMin(&bq[4], __float_as_uint(fb2)); atomicMax(&bq[5], __float_as_uint(fb2));
}

// ===== D3: maskchunks (blocks 0..287) + iteration-0 softmax (288..359) =====
__global__ __launch_bounds__(256) void masksoft_kernel(
    const float* __restrict__ bnd, unsigned short* __restrict__ jlist,
    int* __restrict__ cnt, int* __restrict__ wl, unsigned* __restrict__ wlc,
    const unsigned* __restrict__ sent,
    const float* __restrict__ q, const int* __restrict__ spos,
    unsigned short* __restrict__ smpb, unsigned short* __restrict__ smht,
    float* __restrict__ part)
{
    int tid = threadIdx.x;
    if (blockIdx.x < 288) {
        int lane = tid & 63;
        int bt = blockIdx.x * 4 + (tid >> 6);
        if (bt >= BB * NT16) return;
        int b = bt / NT16;
        const float* tb = bnd + (size_t)bt * 6;
        float tlo0 = tb[0], thi0 = tb[1], tlo1 = tb[2], thi1 = tb[3], tlo2 = tb[4], thi2 = tb[5];
        unsigned short* jl = jlist + (size_t)bt * NJB;
        const float* bb = bnd + (size_t)b * NT16 * 6;
        int n = 0;
#pragma unroll
        for (int r = 0; r < 5; r++) {
            int jb = r * 64 + lane;
            bool keep = false;
            if (jb < NJB) {
                const float* a0 = bb + (size_t)(2 * jb) * 6;
                float s = 0.f;
#pragma unroll
                for (int f = 0; f < 3; f++) {
                    float jlo = fminf(a0[2 * f], a0[6 + 2 * f]);
                    float jhi = fmaxf(a0[2 * f + 1], a0[6 + 2 * f + 1]);
                    float lo = (f == 0) ? tlo0 : (f == 1) ? tlo1 : tlo2;
                    float hi = (f == 0) ? thi0 : (f == 1) ? thi1 : thi2;
                    float gap = fmaxf(0.f, fmaxf(lo - jhi, jlo - hi));
                    s = fmaf(gap, gap, s);
                }
                keep = (s <= PRUNE_T);
            }
            unsigned long long m = __ballot(keep);
            if (keep) {
                int pre = __popcll(m & ((1ull << lane) - 1ull));
                jl[n + pre] = (unsigned short)jb;
            }
            n += __popcll(m);
        }
        if (lane == 0) {
            cnt[bt] = n;
            int nsl = (n + CHK - 1) / CHK;
            if (nsl > 0) {
                int base = (int)(atomicAdd(wlc, (unsigned)nsl) - sent[0]);
                for (int s2 = 0; s2 < nsl; s2++) wl[base + s2] = bt * 64 + s2;
            }
        }
        return;
    }
    int idx = (blockIdx.x - 288) * 256 + tid;
    if (idx >= BB * NN) return;
    int b = idx / NN, p = idx - b * NN;
    const float* qp = q + (size_t)idx * CC;
    float v[CC], m = -1e30f;
#pragma unroll
    for (int c = 0; c < CC; c++) { v[c] = qp[c]; m = fmaxf(m, v[c]); }
    float ssum = 0.f;
#pragma unroll
    for (int c = 0; c < CC; c++) { v[c] = __expf(v[c] - m); ssum += v[c]; }
    float inv = 1.0f / ssum;
    int s = spos[idx];
#pragma unroll
    for (int c = 0; c < CC; c++) {
        unsigned short h = bf16_1(v[c] * inv);
        smpb[(size_t)(b * CC + c) * NN + p] = h;
        smht[(size_t)(b * 32 + c) * NN + s] = h;
    }
    float* pp = part + (size_t)(b * NN + s) * 24;
#pragma unroll
    for (int k = 0; k < 24; k++) pp[k] = 0.f;
}

// ---------------- bilateral helpers (depth-2 pipelined j-set) --------------
struct JSet { float vf[5][8]; short8 sb0, sb1; };

static __device__ __forceinline__ void load_jset(
    JSet& s, const float* __restrict__ fb, const unsigned short* __restrict__ smb,
    int jb, int quad, int l16)
{
    int coff = jb * 32 + quad * 8;
#pragma unroll
    for (int f = 0; f < 5; f++) {
        const float4* pf = (const float4*)(fb + (size_t)f * NN + coff);
        float4 lo = pf[0], hi = pf[1];
        s.vf[f][0] = lo.x; s.vf[f][1] = lo.y; s.vf[f][2] = lo.z; s.vf[f][3] = lo.w;
        s.vf[f][4] = hi.x; s.vf[f][5] = hi.y; s.vf[f][6] = hi.z; s.vf[f][7] = hi.w;
    }
    s.sb0 = *(const short8*)(smb + (size_t)l16 * NN + coff);
    s.sb1 = *(const short8*)(smb + (size_t)(16 + l16) * NN + coff);
}

static __device__ __forceinline__ void compute_jset(
    const JSet& s, float fi0, float fi1, float fi2, float fi3, float fi4,
    f32x4& acc0, f32x4& acc1)
{
    float kf[8];
#pragma unroll
    for (int e = 0; e < 8; e++) {
        float d0 = s.vf[0][e] - fi0;
        float d1 = s.vf[1][e] - fi1;
        float d2 = s.vf[2][e] - fi2;
        float d3 = s.vf[3][e] - fi3;
        float d4 = s.vf[4][e] - fi4;
        float sm = d0 * d0;
        sm = fmaf(d1, d1, sm);
        sm = fmaf(d2, d2, sm);
        sm = fmaf(d3, d3, sm);
        sm = fmaf(d4, d4, sm);
        kf[e] = __builtin_amdgcn_exp2f(-sm);
    }
    int4v ap = { (int)pk_bf16(kf[0], kf[1]), (int)pk_bf16(kf[2], kf[3]),
                 (int)pk_bf16(kf[4], kf[5]), (int)pk_bf16(kf[6], kf[7]) };
    short8 afrag = __builtin_bit_cast(short8, ap);
    acc0 = __builtin_amdgcn_mfma_f32_16x16x32_bf16(afrag, s.sb0, acc0, 0, 0, 0);
    acc1 = __builtin_amdgcn_mfma_f32_16x16x32_bf16(afrag, s.sb1, acc1, 0, 0, 0);
}

// ===== K2: conv + bilateral, independent block roles (no sync) =============
__global__ __launch_bounds__(256) void conv_bil_kernel(
    const unsigned short* __restrict__ smpb, const unsigned short* __restrict__ gbt,
    const float* __restrict__ sxt, float* __restrict__ spf,
    const unsigned short* __restrict__ smht_c, const float* __restrict__ fjs,
    const unsigned short* __restrict__ jlist, const int* __restrict__ cntv,
    const int* __restrict__ wl, const unsigned* __restrict__ wlc,
    const unsigned* __restrict__ sent, float* __restrict__ part)
{
    __shared__ unsigned short C1t[96 * GST];   // conv role only (20 KB)
    int tid = threadIdx.x;
    int lane = tid & 63, w = tid >> 6;
    int quad = lane >> 4, l16 = lane & 15;
    int bid = blockIdx.x;

    if (bid < NCONV) {
        const unsigned short* plane = smpb + (size_t)bid * NN;
        for (int mt = w; mt < 6; mt += 4) {
            int m0 = mt * 16;
            short8 a[3];
#pragma unroll
            for (int kk = 0; kk < 3; kk++)
                a[kk] = *(const short8*)(plane + (size_t)(m0 + l16) * 96 + kk * 32 + quad * 8);
            f32x4 acc[6];
#pragma unroll
            for (int nt = 0; nt < 6; nt++) acc[nt] = (f32x4){0.f, 0.f, 0.f, 0.f};
#pragma unroll
            for (int nt = 0; nt < 6; nt++) {
#pragma unroll
                for (int kk = 0; kk < 3; kk++) {
                    short8 bf = *(const short8*)(gbt + (nt * 16 + l16) * 96 + kk * 32 + quad * 8);
                    acc[nt] = __builtin_amdgcn_mfma_f32_16x16x32_bf16(a[kk], bf, acc[nt], 0, 0, 0);
                }
            }
#pragma unroll
            for (int nt = 0; nt < 6; nt++) {
                unsigned* dst = (unsigned*)&C1t[(nt * 16 + l16) * GST + m0 + quad * 4];
                dst[0] = pk_bf16(acc[nt][0], acc[nt][1]);
                dst[1] = pk_bf16(acc[nt][2], acc[nt][3]);
            }
        }
        __syncthreads();
        float* outp = spf + (size_t)bid * NN;
        for (int mt = w; mt < 6; mt += 4) {
            int m0 = mt * 16;
            short8 a[3];
#pragma unroll
            for (int kk = 0; kk < 3; kk++)
                a[kk] = *(const short8*)(gbt + (m0 + l16) * 96 + kk * 32 + quad * 8);
            f32x4 acc[6];
#pragma unroll
            for (int nt = 0; nt < 6; nt++) acc[nt] = (f32x4){0.f, 0.f, 0.f, 0.f};
#pragma unroll
            for (int nt = 0; nt < 6; nt++) {
#pragma unroll
                for (int kk = 0; kk < 3; kk++) {
                    short8 bf = *(const short8*)&C1t[(nt * 16 + l16) * GST + kk * 32 + quad * 8];
                    acc[nt] = __builtin_amdgcn_mfma_f32_16x16x32_bf16(a[kk], bf, acc[nt], 0, 0, 0);
                }
            }
#pragma unroll
            for (int nt = 0; nt < 6; nt++) {
                int x = nt * 16 + l16;
                float sx = sxt[x];
#pragma unroll
                for (int r = 0; r < 4; r++) {
                    int y = m0 + quad * 4 + r;
                    float invn = __builtin_amdgcn_rcpf(sxt[y] * sx);
                    outp[y * 96 + x] = acc[nt][r] * invn;
                }
            }
        }
        return;
    }

    int nwl = (int)(wlc[0] - sent[0]);
    for (int widx = (bid - NCONV) * 4 + w; widx < nwl; widx += NBIL * 4) {
        int e = wl[widx];
        int bt = e >> 6, ck = e & 63;
        int cnt = min(cntv[bt] - ck * CHK, CHK);
        int b = bt / NT16, tile16 = bt - b * NT16;
        int i = tile16 * 16 + l16;
        const float* fb = fjs + (size_t)b * 5 * NN;
        float fi0 = fb[0 * NN + i], fi1 = fb[1 * NN + i], fi2 = fb[2 * NN + i];
        float fi3 = fb[3 * NN + i], fi4 = fb[4 * NN + i];
        f32x4 acc0 = {0.f, 0.f, 0.f, 0.f};
        f32x4 acc1 = {0.f, 0.f, 0.f, 0.f};
        const unsigned short* smb = smht_c + (size_t)b * 32 * NN;
        const unsigned short* jl = jlist + (size_t)bt * NJB + ck * CHK;
        JSet A, B;
        load_jset(A, fb, smb, jl[0], quad, l16);
        int k = 0;
        while (true) {
            if (k + 1 < cnt) load_jset(B, fb, smb, jl[k + 1], quad, l16);
            compute_jset(A, fi0, fi1, fi2, fi3, fi4, acc0, acc1);
            if (++k >= cnt) break;
            if (k + 1 < cnt) load_jset(A, fb, smb, jl[k + 1], quad, l16);
            compute_jset(B, fi0, fi1, fi2, fi3, fi4, acc0, acc1);
            if (++k >= cnt) break;
        }
        int ibase = tile16 * 16 + quad * 4;
        float* pr = part + (size_t)b * NN * 24;
#pragma unroll
        for (int r = 0; r < 4; r++)
            atomicAdd(&pr[(size_t)(ibase + r) * 24 + l16], acc0[r]);
        if (l16 < 6) {
#pragma unroll
            for (int r = 0; r < 4; r++)
                atomicAdd(&pr[(size_t)(ibase + r) * 24 + 16 + l16], acc1[r]);
        }
    }
}

// ------- K3: norm + messages + update + next-iter softmax (144x128) --------
__global__ __launch_bounds__(128) void update_fused_kernel(
    const float* __restrict__ u, const float* __restrict__ spf,
    float* __restrict__ part, const int* __restrict__ spos,
    const float* __restrict__ Ws, const float* __restrict__ Wb,
    const float* __restrict__ M, float* __restrict__ qout,
    unsigned short* __restrict__ smpb, unsigned short* __restrict__ smht, int wr)
{
    __shared__ float sWs[441], sWb[441], sM[441];
    for (int t = threadIdx.x; t < 441; t += 128) {
        sWs[t] = Ws[t]; sWb[t] = Wb[t]; sM[t] = M[t];
    }
    __syncthreads();
    int idx = blockIdx.x * 128 + threadIdx.x;
    if (idx >= BB * NN) return;
    int b = idx / NN, p = idx - b * NN;
    int s = spos[idx];
    float* pp = part + (size_t)(b * NN + s) * 24;
    float blv[22];
#pragma unroll
    for (int c = 0; c < 22; c++) blv[c] = pp[c];
    float ninv = 1.0f / blv[21];
    float spv[CC], msg[CC];
#pragma unroll
    for (int c = 0; c < CC; c++) {
        blv[c] *= ninv;
        spv[c] = spf[(size_t)(b * CC + c) * NN + p];
    }
#pragma unroll
    for (int c = 0; c < CC; c++) {
        float a = 0.f;
        const float* wr2 = &sWs[c * CC];
        const float* br = &sWb[c * CC];
#pragma unroll
        for (int c2 = 0; c2 < CC; c2++) a = fmaf(wr2[c2], spv[c2], a);
#pragma unroll
        for (int c2 = 0; c2 < CC; c2++) a = fmaf(br[c2], blv[c2], a);
        msg[c] = a;
    }
    const float* up = u + (size_t)idx * CC;
    float qv[CC];
#pragma unroll
    for (int c = 0; c < CC; c++) {
        float a = up[c];
        const float* mr = &sM[c * CC];
#pragma unroll
        for (int c2 = 0; c2 < CC; c2++) a = fmaf(-mr[c2], msg[c2], a);
        qv[c] = a;
    }
    if (wr) {
        float m = -1e30f;
#pragma unroll
        for (int c = 0; c < CC; c++) m = fmaxf(m, qv[c]);
        float ssum = 0.f;
        float ev[CC];
#pragma unroll
        for (int c = 0; c < CC; c++) { ev[c] = __expf(qv[c] - m); ssum += ev[c]; }
        float inv = 1.0f / ssum;
#pragma unroll
        for (int c = 0; c < CC; c++) {
            unsigned short h = bf16_1(ev[c] * inv);
            smpb[(size_t)(b * CC + c) * NN + p] = h;
            smht[(size_t)(b * 32 + c) * NN + s] = h;
        }
#pragma unroll
        for (int k = 0; k < 24; k++) pp[k] = 0.f;
    } else {
        float* qp = qout + (size_t)idx * CC;
#pragma unroll
        for (int c = 0; c < CC; c++) qp[c] = qv[c];
    }
}

extern "C" void kernel_launch(void* const* d_in, const int* in_sizes, int n_in,
                              void* d_out, int out_size, void* d_ws, size_t ws_size,
                              hipStream_t stream)
{
    const float* unary = (const float*)d_in[0];  // [B,H,W,C]
    const float* rgb   = (const float*)d_in[1];  // [B,H,W,3]
    const float* Ws    = (const float*)d_in[2];
    const float* Wb    = (const float*)d_in[3];
    const float* M     = (const float*)d_in[4];
    float* out = (float*)d_out;                  // [B,N,C]

    float* SXT  = (float*)d_ws;                            // 96
    float* FJS  = SXT + 96;                                // B*5*N
    float* SPF  = FJS + (size_t)BB * 5 * NN;               // B*21*N
    float* PART = SPF + (size_t)BB * CC * NN;              // B*N*24
    unsigned* BND = (unsigned*)(PART + (size_t)BB * NN * 24);  // B*576*6
    int*   SPOS = (int*)(BND + (size_t)BB * NT16 * 6);     // B*N
    unsigned* GHA = (unsigned*)(SPOS + BB * NN);           // B*4096 (poison-based)
    unsigned* GHB = GHA + BB * 4096;                       // B*4096 (poison-based)
    int*   CNT  = (int*)(GHB + BB * 4096);                 // B*576
    unsigned* WLC = (unsigned*)(CNT + BB * NT16);          // 1 (poison-based)
    unsigned* SENT = WLC + 1;                              // 1 (NEVER written)
    int*   WL   = (int*)(SENT + 1);                        // <= B*576*36
    unsigned short* JL = (unsigned short*)(WL + BB * NT16 * 36);  // B*576*288
    unsigned short* SMHT = JL + (size_t)BB * NT16 * NJB;   // B*32*N
    unsigned short* SMPB = SMHT + (size_t)BB * 32 * NN;    // B*21*N
    unsigned short* GBT  = SMPB + (size_t)BB * CC * NN;    // 96*96

    histprep_kernel<<<104, 256, 0, stream>>>(rgb, GHA, GHB, SXT, GBT, SMHT, BND);
    scanscatter_kernel<<<BB * 36, 256, 0, stream>>>(rgb, GHA, GHB, SENT, SPOS, FJS, BND);
    masksoft_kernel<<<360, 256, 0, stream>>>((const float*)BND, JL, CNT, WL, WLC, SENT,
                                             unary, SPOS, SMPB, SMHT, PART);
    for (int it = 0; it < 5; ++it) {
        conv_bil_kernel<<<NCONV + NBIL, 256, 0, stream>>>(
            SMPB, GBT, SXT, SPF, SMHT, FJS, JL, CNT, WL, WLC, SENT, PART);
        update_fused_kernel<<<(BB * NN + 127) / 128, 128, 0, stream>>>(
            unary, SPF, PART, SPOS, Ws, Wb, M, out, SMPB, SMHT, (it < 4) ? 1 : 0);
    }
}